// Round 3
// baseline (882.614 us; speedup 1.0000x reference)
//
#include <hip/hip_runtime.h>
#include <math.h>

typedef unsigned short u16;
typedef unsigned int u32;
typedef __attribute__((ext_vector_type(8))) short short8; // 8 x bf16 (4 VGPRs)
typedef __attribute__((ext_vector_type(4))) float f32x4;

__device__ __forceinline__ float b2f(u16 u) {
    u32 x = ((u32)u) << 16;
    return __builtin_bit_cast(float, x);
}
__device__ __forceinline__ u16 f2b(float f) { // RNE bf16
    u32 x = __builtin_bit_cast(u32, f);
    u32 r = x + 0x7fffu + ((x >> 16) & 1u);
    return (u16)(r >> 16);
}
__device__ __forceinline__ void split_hl(float x, u16& h, u16& l) {
    u16 hb = f2b(x);
    h = hb;
    l = f2b(x - b2f(hb));
}
__device__ __forceinline__ float gelu_new_f(float x) {
    const float c = 0.7978845608028654f;
    return 0.5f * x * (1.0f + tanhf(c * (x + 0.044715f * x * x * x)));
}
// breadcrumb: NaN OR inf -> stage-distinctive magnitude
__device__ __forceinline__ float scrub(float v, float s) {
    return (fabsf(v) < 1e25f) ? v : s;
}

// -------- transpose+convert: src fp32 [R][C] -> dst bf16 [C][R] ------------
__global__ __launch_bounds__(256) void transpose_cvt(const float* __restrict__ src,
                                                     u16* __restrict__ dst, int R, int C) {
    __shared__ u16 t[32][33];
    int c0 = blockIdx.x * 32, r0 = blockIdx.y * 32;
    int x = threadIdx.x & 31, y = threadIdx.x >> 5; // 32 x 8
#pragma unroll
    for (int i = 0; i < 32; i += 8)
        t[y + i][x] = f2b(src[(size_t)(r0 + y + i) * C + c0 + x]);
    __syncthreads();
#pragma unroll
    for (int i = 0; i < 32; i += 8)
        dst[(size_t)(c0 + y + i) * R + r0 + x] = t[x][y + i];
}

// -------- T5 rel-pos bias table + additive mask (fp32 inputs) --------------
__global__ void bias_table_kernel(const float* __restrict__ rel_bias,
                                  const float* __restrict__ mask,
                                  float* __restrict__ tab,
                                  float* __restrict__ mask_add) {
    int idx = blockIdx.x * 256 + threadIdx.x; // 0..4095
    if (idx < 4095) {
        int rel = idx - 2047;
        int ret = rel > 0 ? 16 : 0;
        int n = rel < 0 ? -rel : rel;
        int bucket;
        if (n < 8) {
            bucket = ret + n;
        } else {
            int v = 8 + (int)(logf((float)n * 0.125f) * (8.0f / 2.7725887222397811f));
            v = v < 15 ? v : 15;
            bucket = ret + v;
        }
#pragma unroll
        for (int h = 0; h < 16; h++)
            tab[h * 4096 + idx] = rel_bias[bucket * 16 + h];
    }
    if (idx < 4096)
        mask_add[idx] = (1.0f - mask[idx]) * -10000.0f;
}

// -------- RMSNorm: fp32 in -> bf16 hi (+ optional lo plane) ----------------
__global__ __launch_bounds__(256) void rmsnorm_k(const float* __restrict__ X,
                                                 const float* __restrict__ W,
                                                 u16* __restrict__ Yh,
                                                 u16* __restrict__ Yl) {
    __shared__ float red[4];
    int row = blockIdx.x, tid = threadIdx.x;
    const float* xr = X + (size_t)row * 1024;
    float4 x = *(const float4*)(xr + tid * 4);
    float ss = x.x * x.x + x.y * x.y + x.z * x.z + x.w * x.w;
#pragma unroll
    for (int off = 32; off; off >>= 1) ss += __shfl_xor(ss, off, 64);
    if ((tid & 63) == 0) red[tid >> 6] = ss;
    __syncthreads();
    float tot = red[0] + red[1] + red[2] + red[3];
    float s = rsqrtf(tot * (1.0f / 1024.0f) + 1e-6f);
    float4 w4 = *(const float4*)(W + tid * 4);
    float y0 = scrub(x.x * s * w4.x, 1e3f);
    float y1 = scrub(x.y * s * w4.y, 1e3f);
    float y2 = scrub(x.z * s * w4.z, 1e3f);
    float y3 = scrub(x.w * s * w4.w, 1e3f);
    u16 h0, h1, h2, h3, l0, l1, l2, l3;
    split_hl(y0, h0, l0); split_hl(y1, h1, l1);
    split_hl(y2, h2, l2); split_hl(y3, h3, l3);
    uint2 oh, ol;
    oh.x = (u32)h0 | ((u32)h1 << 16);
    oh.y = (u32)h2 | ((u32)h3 << 16);
    *(uint2*)(Yh + (size_t)row * 1024 + tid * 4) = oh;
    if (Yl) {
        ol.x = (u32)l0 | ((u32)l1 << 16);
        ol.y = (u32)l2 | ((u32)l3 << 16);
        *(uint2*)(Yl + (size_t)row * 1024 + tid * 4) = ol;
    }
}

// -------- GEMM (plain A): C = A[M,K] @ Bt[N,K]^T (+Res) --------------------
// MODE 1: C fp32 = acc + fp32 Res.  128x128 tile, BK=32, 4 waves.
__global__ __launch_bounds__(256) void gemm_bt_res(const u16* __restrict__ A,
                                                   const u16* __restrict__ Bt,
                                                   float* __restrict__ C,
                                                   const float* __restrict__ Res,
                                                   int M, int N, int K, float sval) {
    constexpr int LDSS = 40;
    __shared__ __align__(16) u16 As[128 * LDSS];
    __shared__ __align__(16) u16 Bs[128 * LDSS];
    int tid = threadIdx.x;
    int wave = tid >> 6, lane = tid & 63, quad = lane >> 4, l15 = lane & 15;
    int bm = blockIdx.y * 128, bn = blockIdx.x * 128;
    int wm = (wave >> 1) * 64, wn = (wave & 1) * 64;
    f32x4 acc[4][4] = {};
    int sr = tid >> 2, sc = (tid & 3) * 8;
    const u16* a0 = A + (size_t)(bm + sr) * K + sc;
    const u16* a1 = a0 + (size_t)64 * K;
    const u16* b0 = Bt + (size_t)(bn + sr) * K + sc;
    const u16* b1 = b0 + (size_t)64 * K;
    u16* as0 = As + sr * LDSS + sc;
    u16* as1 = As + (sr + 64) * LDSS + sc;
    u16* bs0 = Bs + sr * LDSS + sc;
    u16* bs1 = Bs + (sr + 64) * LDSS + sc;
    for (int k0 = 0; k0 < K; k0 += 32) {
        __syncthreads();
        *(int4*)as0 = *(const int4*)(a0 + k0);
        *(int4*)as1 = *(const int4*)(a1 + k0);
        *(int4*)bs0 = *(const int4*)(b0 + k0);
        *(int4*)bs1 = *(const int4*)(b1 + k0);
        __syncthreads();
        short8 af[4], bf[4];
#pragma unroll
        for (int i = 0; i < 4; i++)
            af[i] = *(const short8*)(As + (wm + i * 16 + l15) * LDSS + quad * 8);
#pragma unroll
        for (int j = 0; j < 4; j++)
            bf[j] = *(const short8*)(Bs + (wn + j * 16 + l15) * LDSS + quad * 8);
#pragma unroll
        for (int i = 0; i < 4; i++)
#pragma unroll
            for (int j = 0; j < 4; j++)
                acc[i][j] = __builtin_amdgcn_mfma_f32_16x16x32_bf16(af[i], bf[j], acc[i][j], 0, 0, 0);
    }
#pragma unroll
    for (int i = 0; i < 4; i++)
#pragma unroll
        for (int j = 0; j < 4; j++) {
            int col = bn + wn + j * 16 + l15;
#pragma unroll
            for (int r = 0; r < 4; r++) {
                int row = bm + wm + i * 16 + quad * 4 + r;
                float v = acc[i][j][r] + Res[(size_t)row * N + col];
                C[(size_t)row * N + col] = scrub(v, sval);
            }
        }
}

// -------- GEMM (split-A hi/lo): acc = (Ah+Al)[M,K] @ Bt[N,K]^T -------------
// MODE 0: C bf16; MODE 2: C fp32. (for QKV projections)
template <int MODE>
__global__ __launch_bounds__(256) void gemm_bt_sa(const u16* __restrict__ Ah,
                                                  const u16* __restrict__ Al,
                                                  const u16* __restrict__ Bt,
                                                  void* __restrict__ Cv,
                                                  int M, int N, int K, float sval) {
    constexpr int LDSS = 40;
    __shared__ __align__(16) u16 Ash[128 * LDSS];
    __shared__ __align__(16) u16 Asl[128 * LDSS];
    __shared__ __align__(16) u16 Bs[128 * LDSS];
    int tid = threadIdx.x;
    int wave = tid >> 6, lane = tid & 63, quad = lane >> 4, l15 = lane & 15;
    int bm = blockIdx.y * 128, bn = blockIdx.x * 128;
    int wm = (wave >> 1) * 64, wn = (wave & 1) * 64;
    f32x4 acc[4][4] = {};
    int sr = tid >> 2, sc = (tid & 3) * 8;
    const u16* ah0 = Ah + (size_t)(bm + sr) * K + sc;
    const u16* ah1 = ah0 + (size_t)64 * K;
    const u16* al0 = Al + (size_t)(bm + sr) * K + sc;
    const u16* al1 = al0 + (size_t)64 * K;
    const u16* b0 = Bt + (size_t)(bn + sr) * K + sc;
    const u16* b1 = b0 + (size_t)64 * K;
    u16* ash0 = Ash + sr * LDSS + sc;
    u16* ash1 = Ash + (sr + 64) * LDSS + sc;
    u16* asl0 = Asl + sr * LDSS + sc;
    u16* asl1 = Asl + (sr + 64) * LDSS + sc;
    u16* bs0 = Bs + sr * LDSS + sc;
    u16* bs1 = Bs + (sr + 64) * LDSS + sc;
    for (int k0 = 0; k0 < K; k0 += 32) {
        __syncthreads();
        *(int4*)ash0 = *(const int4*)(ah0 + k0);
        *(int4*)ash1 = *(const int4*)(ah1 + k0);
        *(int4*)asl0 = *(const int4*)(al0 + k0);
        *(int4*)asl1 = *(const int4*)(al1 + k0);
        *(int4*)bs0 = *(const int4*)(b0 + k0);
        *(int4*)bs1 = *(const int4*)(b1 + k0);
        __syncthreads();
        short8 afh[4], afl[4], bf[4];
#pragma unroll
        for (int i = 0; i < 4; i++) {
            afh[i] = *(const short8*)(Ash + (wm + i * 16 + l15) * LDSS + quad * 8);
            afl[i] = *(const short8*)(Asl + (wm + i * 16 + l15) * LDSS + quad * 8);
        }
#pragma unroll
        for (int j = 0; j < 4; j++)
            bf[j] = *(const short8*)(Bs + (wn + j * 16 + l15) * LDSS + quad * 8);
#pragma unroll
        for (int i = 0; i < 4; i++)
#pragma unroll
            for (int j = 0; j < 4; j++) {
                acc[i][j] = __builtin_amdgcn_mfma_f32_16x16x32_bf16(afh[i], bf[j], acc[i][j], 0, 0, 0);
                acc[i][j] = __builtin_amdgcn_mfma_f32_16x16x32_bf16(afl[i], bf[j], acc[i][j], 0, 0, 0);
            }
    }
#pragma unroll
    for (int i = 0; i < 4; i++)
#pragma unroll
        for (int j = 0; j < 4; j++) {
            int col = bn + wn + j * 16 + l15;
#pragma unroll
            for (int r = 0; r < 4; r++) {
                int row = bm + wm + i * 16 + quad * 4 + r;
                float v = scrub(acc[i][j][r], sval);
                if (MODE == 0)
                    ((u16*)Cv)[(size_t)row * N + col] = f2b(v);
                else
                    ((float*)Cv)[(size_t)row * N + col] = v;
            }
        }
}

// -------- Dual GEMM + gated GELU: C = gelu(A@B1t^T) * (A@B2t^T), bf16 ------
__global__ __launch_bounds__(256) void gemm_dual_gelu(const u16* __restrict__ A,
                                                      const u16* __restrict__ B1t,
                                                      const u16* __restrict__ B2t,
                                                      u16* __restrict__ C,
                                                      int M, int N, int K) {
    constexpr int LDSS = 40;
    __shared__ __align__(16) u16 As[128 * LDSS];
    __shared__ __align__(16) u16 B1s[128 * LDSS];
    __shared__ __align__(16) u16 B2s[128 * LDSS];
    int tid = threadIdx.x;
    int wave = tid >> 6, lane = tid & 63, quad = lane >> 4, l15 = lane & 15;
    int bm = blockIdx.y * 128, bn = blockIdx.x * 128;
    int wm = (wave >> 1) * 64, wn = (wave & 1) * 64;
    f32x4 acc1[4][4] = {};
    f32x4 acc2[4][4] = {};
    int sr = tid >> 2, sc = (tid & 3) * 8;
    const u16* a0 = A + (size_t)(bm + sr) * K + sc;
    const u16* a1 = a0 + (size_t)64 * K;
    const u16* p10 = B1t + (size_t)(bn + sr) * K + sc;
    const u16* p11 = p10 + (size_t)64 * K;
    const u16* p20 = B2t + (size_t)(bn + sr) * K + sc;
    const u16* p21 = p20 + (size_t)64 * K;
    u16* as0 = As + sr * LDSS + sc;
    u16* as1 = As + (sr + 64) * LDSS + sc;
    u16* b1s0 = B1s + sr * LDSS + sc;
    u16* b1s1 = B1s + (sr + 64) * LDSS + sc;
    u16* b2s0 = B2s + sr * LDSS + sc;
    u16* b2s1 = B2s + (sr + 64) * LDSS + sc;
    for (int k0 = 0; k0 < K; k0 += 32) {
        __syncthreads();
        *(int4*)as0 = *(const int4*)(a0 + k0);
        *(int4*)as1 = *(const int4*)(a1 + k0);
        *(int4*)b1s0 = *(const int4*)(p10 + k0);
        *(int4*)b1s1 = *(const int4*)(p11 + k0);
        *(int4*)b2s0 = *(const int4*)(p20 + k0);
        *(int4*)b2s1 = *(const int4*)(p21 + k0);
        __syncthreads();
        short8 af[4], b1f[4], b2f_[4];
#pragma unroll
        for (int i = 0; i < 4; i++)
            af[i] = *(const short8*)(As + (wm + i * 16 + l15) * LDSS + quad * 8);
#pragma unroll
        for (int j = 0; j < 4; j++) {
            b1f[j] = *(const short8*)(B1s + (wn + j * 16 + l15) * LDSS + quad * 8);
            b2f_[j] = *(const short8*)(B2s + (wn + j * 16 + l15) * LDSS + quad * 8);
        }
#pragma unroll
        for (int i = 0; i < 4; i++)
#pragma unroll
            for (int j = 0; j < 4; j++) {
                acc1[i][j] = __builtin_amdgcn_mfma_f32_16x16x32_bf16(af[i], b1f[j], acc1[i][j], 0, 0, 0);
                acc2[i][j] = __builtin_amdgcn_mfma_f32_16x16x32_bf16(af[i], b2f_[j], acc2[i][j], 0, 0, 0);
            }
    }
#pragma unroll
    for (int i = 0; i < 4; i++)
#pragma unroll
        for (int j = 0; j < 4; j++) {
            int col = bn + wn + j * 16 + l15;
#pragma unroll
            for (int r = 0; r < 4; r++) {
                int row = bm + wm + i * 16 + quad * 4 + r;
                float v = gelu_new_f(acc1[i][j][r]) * acc2[i][j][r];
                C[(size_t)row * N + col] = f2b(scrub(v, 1e10f));
            }
        }
}

// -------- MFMA flash attention; Q,K fp32 (hi/lo scores), V bf16 ------------
__global__ __launch_bounds__(256) void attn_kernel(const float* __restrict__ Qb,
                                                   const float* __restrict__ Kb,
                                                   const u16* __restrict__ Vb,
                                                   const float* __restrict__ bias_tab,
                                                   const float* __restrict__ mask_add,
                                                   u16* __restrict__ Ctx) {
    constexpr int QS = 72, KS = 72, VS = 40, PS = 40;
    __shared__ __align__(16) u16 Qh[64 * QS];
    __shared__ __align__(16) u16 Ql[64 * QS];
    __shared__ __align__(16) u16 Kh[32 * KS];
    __shared__ __align__(16) u16 Kl[32 * KS];
    __shared__ __align__(16) u16 Vs[64 * VS];   // transposed: [d][k]
    __shared__ __align__(16) u16 Pss[4 * 16 * PS];
    int tid = threadIdx.x, wave = tid >> 6, lane = tid & 63;
    int quad = lane >> 4, l15 = lane & 15;
    int h = blockIdx.y, b = blockIdx.z;
    int q0 = blockIdx.x * 64;
    const size_t rs = 1024;
    const float* Qg = Qb + ((size_t)(b * 2048 + q0)) * rs + h * 64;
    const float* Kg = Kb + ((size_t)(b * 2048)) * rs + h * 64;
    const u16* Vg = Vb + ((size_t)(b * 2048)) * rs + h * 64;
    {   // stage Q tile 64x64 fp32 -> hi/lo
        int r = tid >> 2, c0 = (tid & 3) * 16;
#pragma unroll
        for (int j = 0; j < 4; j++) {
            float4 q4 = *(const float4*)(Qg + (size_t)r * rs + c0 + j * 4);
            u16 hh, ll;
            split_hl(q4.x, hh, ll); Qh[r * QS + c0 + j * 4 + 0] = hh; Ql[r * QS + c0 + j * 4 + 0] = ll;
            split_hl(q4.y, hh, ll); Qh[r * QS + c0 + j * 4 + 1] = hh; Ql[r * QS + c0 + j * 4 + 1] = ll;
            split_hl(q4.z, hh, ll); Qh[r * QS + c0 + j * 4 + 2] = hh; Ql[r * QS + c0 + j * 4 + 2] = ll;
            split_hl(q4.w, hh, ll); Qh[r * QS + c0 + j * 4 + 3] = hh; Ql[r * QS + c0 + j * 4 + 3] = ll;
        }
    }
    f32x4 O[4] = {};
    float m_i[4], l_i[4];
#pragma unroll
    for (int r = 0; r < 4; r++) { m_i[r] = -1e9f; l_i[r] = 0.0f; }
    __syncthreads();
    short8 qh0 = *(const short8*)(Qh + (wave * 16 + l15) * QS + quad * 8);
    short8 qh1 = *(const short8*)(Qh + (wave * 16 + l15) * QS + 32 + quad * 8);
    short8 ql0 = *(const short8*)(Ql + (wave * 16 + l15) * QS + quad * 8);
    short8 ql1 = *(const short8*)(Ql + (wave * 16 + l15) * QS + 32 + quad * 8);
    u16* Pw = Pss + wave * 16 * PS;
    int my_q = q0 + wave * 16 + quad * 4;
    const float* bt = bias_tab + h * 4096;
    const float* ma = mask_add + b * 2048;

    for (int k0 = 0; k0 < 2048; k0 += 32) {
        __syncthreads();
        {   // stage K tile 32x64 fp32 -> hi/lo ; V tile 32x64 bf16 -> [d][k]
            int r = tid >> 3, c0 = (tid & 7) * 8;
#pragma unroll
            for (int j = 0; j < 2; j++) {
                float4 k4 = *(const float4*)(Kg + (size_t)(k0 + r) * rs + c0 + j * 4);
                u16 hh, ll;
                split_hl(k4.x, hh, ll); Kh[r * KS + c0 + j * 4 + 0] = hh; Kl[r * KS + c0 + j * 4 + 0] = ll;
                split_hl(k4.y, hh, ll); Kh[r * KS + c0 + j * 4 + 1] = hh; Kl[r * KS + c0 + j * 4 + 1] = ll;
                split_hl(k4.z, hh, ll); Kh[r * KS + c0 + j * 4 + 2] = hh; Kl[r * KS + c0 + j * 4 + 2] = ll;
                split_hl(k4.w, hh, ll); Kh[r * KS + c0 + j * 4 + 3] = hh; Kl[r * KS + c0 + j * 4 + 3] = ll;
            }
            int4 vv = *(const int4*)(Vg + (size_t)(k0 + r) * rs + c0);
            const u16* vp = (const u16*)&vv;
#pragma unroll
            for (int j = 0; j < 8; j++) Vs[(c0 + j) * VS + r] = vp[j];
        }
        __syncthreads();
        float sv[2][4];
#pragma unroll
        for (int t = 0; t < 2; t++) {
            short8 kh0 = *(const short8*)(Kh + (t * 16 + l15) * KS + quad * 8);
            short8 kh1 = *(const short8*)(Kh + (t * 16 + l15) * KS + 32 + quad * 8);
            short8 kl0 = *(const short8*)(Kl + (t * 16 + l15) * KS + quad * 8);
            short8 kl1 = *(const short8*)(Kl + (t * 16 + l15) * KS + 32 + quad * 8);
            f32x4 z = {0.0f, 0.0f, 0.0f, 0.0f};
            z = __builtin_amdgcn_mfma_f32_16x16x32_bf16(ql0, kh0, z, 0, 0, 0);
            z = __builtin_amdgcn_mfma_f32_16x16x32_bf16(ql1, kh1, z, 0, 0, 0);
            z = __builtin_amdgcn_mfma_f32_16x16x32_bf16(qh0, kl0, z, 0, 0, 0);
            z = __builtin_amdgcn_mfma_f32_16x16x32_bf16(qh1, kl1, z, 0, 0, 0);
            z = __builtin_amdgcn_mfma_f32_16x16x32_bf16(qh0, kh0, z, 0, 0, 0);
            z = __builtin_amdgcn_mfma_f32_16x16x32_bf16(qh1, kh1, z, 0, 0, 0);
            int kcol = k0 + t * 16 + l15;
            float madd = ma[kcol];
#pragma unroll
            for (int r = 0; r < 4; r++)
                sv[t][r] = z[r] + bt[kcol - (my_q + r) + 2047] + madd;
        }
#pragma unroll
        for (int r = 0; r < 4; r++) {
            float mx = fmaxf(sv[0][r], sv[1][r]);
#pragma unroll
            for (int off = 1; off < 16; off <<= 1) mx = fmaxf(mx, __shfl_xor(mx, off, 64));
            float mnew = fmaxf(m_i[r], mx);
            float a = expf(m_i[r] - mnew);
            float p0 = expf(sv[0][r] - mnew);
            float p1 = expf(sv[1][r] - mnew);
            sv[0][r] = p0; sv[1][r] = p1;
            float rsum = p0 + p1;
#pragma unroll
            for (int off = 1; off < 16; off <<= 1) rsum += __shfl_xor(rsum, off, 64);
            l_i[r] = l_i[r] * a + rsum;
            m_i[r] = mnew;
#pragma unroll
            for (int nt = 0; nt < 4; nt++) O[nt][r] *= a;
        }
#pragma unroll
        for (int t = 0; t < 2; t++)
#pragma unroll
            for (int r = 0; r < 4; r++)
                Pw[(quad * 4 + r) * PS + t * 16 + l15] = f2b(sv[t][r]);
        short8 pf = *(const short8*)(Pw + l15 * PS + quad * 8);
#pragma unroll
        for (int nt = 0; nt < 4; nt++) {
            short8 vf = *(const short8*)(Vs + (nt * 16 + l15) * VS + quad * 8);
            O[nt] = __builtin_amdgcn_mfma_f32_16x16x32_bf16(pf, vf, O[nt], 0, 0, 0);
        }
    }
    u16* Cg = Ctx + ((size_t)(b * 2048 + my_q)) * rs + h * 64;
#pragma unroll
    for (int nt = 0; nt < 4; nt++)
#pragma unroll
        for (int r = 0; r < 4; r++) {
            float v = O[nt][r] / l_i[r];
            Cg[(size_t)r * rs + nt * 16 + l15] = f2b(scrub(v, 1e6f));
        }
}

// ---------------------------------------------------------------------------
extern "C" void kernel_launch(void* const* d_in, const int* in_sizes, int n_in,
                              void* d_out, int out_size, void* d_ws, size_t ws_size,
                              hipStream_t stream) {
    const float* hidden = (const float*)d_in[0];
    const float* mask   = (const float*)d_in[1];
    const float* ln1_w  = (const float*)d_in[2];
    const float* wq     = (const float*)d_in[3];
    const float* wk     = (const float*)d_in[4];
    const float* wv     = (const float*)d_in[5];
    const float* relb   = (const float*)d_in[6];
    const float* wo     = (const float*)d_in[7];
    const float* ln2_w  = (const float*)d_in[8];
    const float* w1     = (const float*)d_in[9];
    const float* w2     = (const float*)d_in[10];
    const float* w_out  = (const float*)d_in[11];
    float* out = (float*)d_out;

    // workspace layout (MB), phase-multiplexed:
    //  0- 8 : normed_hi -> ctx -> normed2
    //  8-16 : normed_lo (dead after QKV)
    // 16-24 : w1T   24-32 : w2T   32-40 : woutT    (bf16)
    // 40-42 : wqT   42-44 : wkT   44-46 : wvT  46-48 : woT  (bf16)
    // 48-49 : bias_tab (256K) + mask_add (16K)
    // 49-65 : kb (fp32)      65-73 : vb (bf16)
    // 41-73 : ffg (bf16, after attention+out-proj; overlays dead regions)
    // qb (fp32) lives in d_out until out-proj overwrites it with the trunk.
    char* w = (char*)d_ws;
    const size_t MB = 1u << 20;
    u16*   normedh = (u16*)(w + 0 * MB);
    u16*   normedl = (u16*)(w + 8 * MB);
    u16*   ctx     = (u16*)(w + 0 * MB);
    u16*   normed2 = (u16*)(w + 0 * MB);
    u16*   w1T     = (u16*)(w + 16 * MB);
    u16*   w2T     = (u16*)(w + 24 * MB);
    u16*   woutT   = (u16*)(w + 32 * MB);
    u16*   wqT     = (u16*)(w + 40 * MB);
    u16*   wkT     = (u16*)(w + 42 * MB);
    u16*   wvT     = (u16*)(w + 44 * MB);
    u16*   woT     = (u16*)(w + 46 * MB);
    float* bias_tab = (float*)(w + 48 * MB);
    float* mask_add = (float*)(w + 48 * MB + 256 * 1024);
    float* kb      = (float*)(w + 49 * MB);
    u16*   vb      = (u16*)(w + 65 * MB);
    u16*   ffg     = (u16*)(w + 41 * MB);
    float* qb      = (float*)d_out;

    dim3 blk(256);
    // weight transposes fp32 -> bf16 [N][K]
    transpose_cvt<<<dim3(32, 32), blk, 0, stream>>>(wq, wqT, 1024, 1024);
    transpose_cvt<<<dim3(32, 32), blk, 0, stream>>>(wk, wkT, 1024, 1024);
    transpose_cvt<<<dim3(32, 32), blk, 0, stream>>>(wv, wvT, 1024, 1024);
    transpose_cvt<<<dim3(32, 32), blk, 0, stream>>>(wo, woT, 1024, 1024);
    transpose_cvt<<<dim3(128, 32), blk, 0, stream>>>(w1, w1T, 1024, 4096);
    transpose_cvt<<<dim3(128, 32), blk, 0, stream>>>(w2, w2T, 1024, 4096);
    transpose_cvt<<<dim3(32, 128), blk, 0, stream>>>(w_out, woutT, 4096, 1024);
    bias_table_kernel<<<16, 256, 0, stream>>>(relb, mask, bias_tab, mask_add);

    // pre-LN 1 (hi+lo planes) + QKV (split-A; q,k fp32; v bf16)
    rmsnorm_k<<<4096, blk, 0, stream>>>(hidden, ln1_w, normedh, normedl);
    gemm_bt_sa<2><<<dim3(8, 32), blk, 0, stream>>>(normedh, normedl, wqT, qb, 4096, 1024, 1024, 1e4f);
    gemm_bt_sa<2><<<dim3(8, 32), blk, 0, stream>>>(normedh, normedl, wkT, kb, 4096, 1024, 1024, 1e4f);
    gemm_bt_sa<0><<<dim3(8, 32), blk, 0, stream>>>(normedh, normedl, wvT, vb, 4096, 1024, 1024, 1e4f);

    // attention (ctx overwrites dead normed_hi region)
    attn_kernel<<<dim3(32, 16, 2), blk, 0, stream>>>(qb, kb, vb, bias_tab, mask_add, ctx);

    // output proj + residual -> fp32 trunk in d_out (overwrites qb)
    gemm_bt_res<<<dim3(8, 32), blk, 0, stream>>>(ctx, woT, out, hidden, 4096, 1024, 1024, 1e8f);

    // pre-LN 2 (single plane) + gated FFN + final residual
    rmsnorm_k<<<4096, blk, 0, stream>>>(out, ln2_w, normed2, nullptr);
    gemm_dual_gelu<<<dim3(32, 32), blk, 0, stream>>>(normed2, w1T, w2T, ffg, 4096, 4096, 1024);
    gemm_bt_res<<<dim3(8, 32), blk, 0, stream>>>(ffg, woutT, out, out, 4096, 1024, 4096, 1e12f);
}

// Round 4
// 767.656 us; speedup vs baseline: 1.1498x; 1.1498x over previous
//
#include <hip/hip_runtime.h>
#include <math.h>

typedef unsigned short u16;
typedef unsigned int u32;
typedef __attribute__((ext_vector_type(8))) short short8; // 8 x bf16 (4 VGPRs)
typedef __attribute__((ext_vector_type(4))) float f32x4;

__device__ __forceinline__ float b2f(u16 u) {
    u32 x = ((u32)u) << 16;
    return __builtin_bit_cast(float, x);
}
__device__ __forceinline__ u16 f2b(float f) { // RNE bf16
    u32 x = __builtin_bit_cast(u32, f);
    u32 r = x + 0x7fffu + ((x >> 16) & 1u);
    return (u16)(r >> 16);
}
__device__ __forceinline__ void split_hl(float x, u16& h, u16& l) {
    u16 hb = f2b(x);
    h = hb;
    l = f2b(x - b2f(hb));
}
__device__ __forceinline__ float gelu_new_f(float x) {
    const float c = 0.7978845608028654f;
    return 0.5f * x * (1.0f + tanhf(c * (x + 0.044715f * x * x * x)));
}
// breadcrumb: NaN OR inf -> stage-distinctive magnitude
__device__ __forceinline__ float scrub(float v, float s) {
    return (fabsf(v) < 1e25f) ? v : s;
}
// async global->LDS, 16B per lane; LDS dest = wave-uniform base + lane*16
__device__ __forceinline__ void gld16(const void* g, void* l) {
    __builtin_amdgcn_global_load_lds((const __attribute__((address_space(1))) u32*)g,
                                     (__attribute__((address_space(3))) u32*)l,
                                     16, 0, 0);
}
__device__ __forceinline__ short8 ldf(const u16* p) { return *(const short8*)p; }

// -------- transpose+convert: src fp32 [R][C] -> dst bf16 [C][R] ------------
__global__ __launch_bounds__(256) void transpose_cvt(const float* __restrict__ src,
                                                     u16* __restrict__ dst, int R, int C) {
    __shared__ u16 t[32][33];
    int c0 = blockIdx.x * 32, r0 = blockIdx.y * 32;
    int x = threadIdx.x & 31, y = threadIdx.x >> 5; // 32 x 8
#pragma unroll
    for (int i = 0; i < 32; i += 8)
        t[y + i][x] = f2b(src[(size_t)(r0 + y + i) * C + c0 + x]);
    __syncthreads();
#pragma unroll
    for (int i = 0; i < 32; i += 8)
        dst[(size_t)(c0 + y + i) * R + r0 + x] = t[x][y + i];
}

// -------- T5 rel-pos bias table + additive mask (fp32 inputs) --------------
__global__ void bias_table_kernel(const float* __restrict__ rel_bias,
                                  const float* __restrict__ mask,
                                  float* __restrict__ tab,
                                  float* __restrict__ mask_add) {
    int idx = blockIdx.x * 256 + threadIdx.x; // 0..4095
    if (idx < 4095) {
        int rel = idx - 2047;
        int ret = rel > 0 ? 16 : 0;
        int n = rel < 0 ? -rel : rel;
        int bucket;
        if (n < 8) {
            bucket = ret + n;
        } else {
            int v = 8 + (int)(logf((float)n * 0.125f) * (8.0f / 2.7725887222397811f));
            v = v < 15 ? v : 15;
            bucket = ret + v;
        }
#pragma unroll
        for (int h = 0; h < 16; h++)
            tab[h * 4096 + idx] = rel_bias[bucket * 16 + h];
    }
    if (idx < 4096)
        mask_add[idx] = (1.0f - mask[idx]) * -10000.0f;
}

// -------- RMSNorm: fp32 in -> bf16 hi (+ optional lo plane) ----------------
__global__ __launch_bounds__(256) void rmsnorm_k(const float* __restrict__ X,
                                                 const float* __restrict__ W,
                                                 u16* __restrict__ Yh,
                                                 u16* __restrict__ Yl) {
    __shared__ float red[4];
    int row = blockIdx.x, tid = threadIdx.x;
    const float* xr = X + (size_t)row * 1024;
    float4 x = *(const float4*)(xr + tid * 4);
    float ss = x.x * x.x + x.y * x.y + x.z * x.z + x.w * x.w;
#pragma unroll
    for (int off = 32; off; off >>= 1) ss += __shfl_xor(ss, off, 64);
    if ((tid & 63) == 0) red[tid >> 6] = ss;
    __syncthreads();
    float tot = red[0] + red[1] + red[2] + red[3];
    float s = rsqrtf(tot * (1.0f / 1024.0f) + 1e-6f);
    float4 w4 = *(const float4*)(W + tid * 4);
    float y0 = scrub(x.x * s * w4.x, 1e3f);
    float y1 = scrub(x.y * s * w4.y, 1e3f);
    float y2 = scrub(x.z * s * w4.z, 1e3f);
    float y3 = scrub(x.w * s * w4.w, 1e3f);
    u16 h0, h1, h2, h3, l0, l1, l2, l3;
    split_hl(y0, h0, l0); split_hl(y1, h1, l1);
    split_hl(y2, h2, l2); split_hl(y3, h3, l3);
    uint2 oh, ol;
    oh.x = (u32)h0 | ((u32)h1 << 16);
    oh.y = (u32)h2 | ((u32)h3 << 16);
    *(uint2*)(Yh + (size_t)row * 1024 + tid * 4) = oh;
    if (Yl) {
        ol.x = (u32)l0 | ((u32)l1 << 16);
        ol.y = (u32)l2 | ((u32)l3 << 16);
        *(uint2*)(Yl + (size_t)row * 1024 + tid * 4) = ol;
    }
}

// -------- merged QKV GEMM, split-A hi/lo, K=1024, N=3072 -------------------
// epilogue: Q -> fp32 qb; K -> bf16 hi/lo planes; V -> transposed bf16 vT
__global__ __launch_bounds__(256) void gemm_qkv(const u16* __restrict__ Ah,
                                                const u16* __restrict__ Al,
                                                const u16* __restrict__ Bt,
                                                float* __restrict__ qb,
                                                u16* __restrict__ Kh,
                                                u16* __restrict__ Kl,
                                                u16* __restrict__ vT) {
    const int K = 1024;
    __shared__ __align__(16) u16 Ash[128 * 32];
    __shared__ __align__(16) u16 Asl[128 * 32];
    __shared__ __align__(16) u16 Bs[128 * 32];
    int tid = threadIdx.x;
    int wave = tid >> 6, lane = tid & 63, quad = lane >> 4, l15 = lane & 15;
    int bm = blockIdx.y * 128, bn = blockIdx.x * 128;
    int wm = (wave >> 1) * 64, wn = (wave & 1) * 64;
    f32x4 acc[4][4] = {};
    int srow = wave * 32 + (lane >> 2), scol = (lane & 3) * 8;
    const u16* gah = Ah + (size_t)(bm + srow) * K + scol;
    const u16* gal = Al + (size_t)(bm + srow) * K + scol;
    const u16* gb  = Bt + (size_t)(bn + srow) * K + scol;
    u16* lah = Ash + wave * 1024;
    u16* lal = Asl + wave * 1024;
    u16* lb  = Bs  + wave * 1024;
    for (int k0 = 0; k0 < K; k0 += 32) {
        __syncthreads();
        gld16(gah + k0, lah);           gld16(gah + k0 + 16 * K, lah + 512);
        gld16(gal + k0, lal);           gld16(gal + k0 + 16 * K, lal + 512);
        gld16(gb + k0, lb);             gld16(gb + k0 + 16 * K, lb + 512);
        __syncthreads();
        short8 afh[4], afl[4], bf[4];
#pragma unroll
        for (int i = 0; i < 4; i++) {
            afh[i] = ldf(Ash + (wm + i * 16 + l15) * 32 + quad * 8);
            afl[i] = ldf(Asl + (wm + i * 16 + l15) * 32 + quad * 8);
        }
#pragma unroll
        for (int j = 0; j < 4; j++)
            bf[j] = ldf(Bs + (wn + j * 16 + l15) * 32 + quad * 8);
#pragma unroll
        for (int i = 0; i < 4; i++)
#pragma unroll
            for (int j = 0; j < 4; j++) {
                acc[i][j] = __builtin_amdgcn_mfma_f32_16x16x32_bf16(afh[i], bf[j], acc[i][j], 0, 0, 0);
                acc[i][j] = __builtin_amdgcn_mfma_f32_16x16x32_bf16(afl[i], bf[j], acc[i][j], 0, 0, 0);
            }
    }
    if (bn < 1024) {            // Q -> fp32
#pragma unroll
        for (int i = 0; i < 4; i++)
#pragma unroll
            for (int j = 0; j < 4; j++) {
                int col = bn + wn + j * 16 + l15;
#pragma unroll
                for (int r = 0; r < 4; r++) {
                    int row = bm + wm + i * 16 + quad * 4 + r;
                    qb[(size_t)row * 1024 + col] = scrub(acc[i][j][r], 1e4f);
                }
            }
    } else if (bn < 2048) {     // K -> hi/lo bf16 planes
#pragma unroll
        for (int i = 0; i < 4; i++)
#pragma unroll
            for (int j = 0; j < 4; j++) {
                int col = bn - 1024 + wn + j * 16 + l15;
#pragma unroll
                for (int r = 0; r < 4; r++) {
                    int row = bm + wm + i * 16 + quad * 4 + r;
                    u16 hh, ll;
                    split_hl(scrub(acc[i][j][r], 1e4f), hh, ll);
                    Kh[(size_t)row * 1024 + col] = hh;
                    Kl[(size_t)row * 1024 + col] = ll;
                }
            }
    } else {                    // V -> transposed bf16 vT[d][B*S]
#pragma unroll
        for (int i = 0; i < 4; i++)
#pragma unroll
            for (int j = 0; j < 4; j++) {
                int col = bn - 2048 + wn + j * 16 + l15;
                int row0 = bm + wm + i * 16 + quad * 4;
                ushort4 p;
                p.x = f2b(scrub(acc[i][j][0], 1e4f));
                p.y = f2b(scrub(acc[i][j][1], 1e4f));
                p.z = f2b(scrub(acc[i][j][2], 1e4f));
                p.w = f2b(scrub(acc[i][j][3], 1e4f));
                *(ushort4*)(vT + (size_t)col * 4096 + row0) = p;
            }
    }
}

// -------- GEMM: C fp32 = A bf16 [M,K] @ Bt [N,K]^T + Res fp32 --------------
__global__ __launch_bounds__(256) void gemm_bt_res(const u16* __restrict__ A,
                                                   const u16* __restrict__ Bt,
                                                   float* __restrict__ C,
                                                   const float* __restrict__ Res,
                                                   int M, int N, int K, float sval) {
    __shared__ __align__(16) u16 As[128 * 32];
    __shared__ __align__(16) u16 Bs[128 * 32];
    int tid = threadIdx.x;
    int wave = tid >> 6, lane = tid & 63, quad = lane >> 4, l15 = lane & 15;
    int bm = blockIdx.y * 128, bn = blockIdx.x * 128;
    int wm = (wave >> 1) * 64, wn = (wave & 1) * 64;
    f32x4 acc[4][4] = {};
    int srow = wave * 32 + (lane >> 2), scol = (lane & 3) * 8;
    const u16* ga = A + (size_t)(bm + srow) * K + scol;
    const u16* gb = Bt + (size_t)(bn + srow) * K + scol;
    u16* la = As + wave * 1024;
    u16* lb = Bs + wave * 1024;
    for (int k0 = 0; k0 < K; k0 += 32) {
        __syncthreads();
        gld16(ga + k0, la);   gld16(ga + k0 + 16 * K, la + 512);
        gld16(gb + k0, lb);   gld16(gb + k0 + 16 * K, lb + 512);
        __syncthreads();
        short8 af[4], bf[4];
#pragma unroll
        for (int i = 0; i < 4; i++)
            af[i] = ldf(As + (wm + i * 16 + l15) * 32 + quad * 8);
#pragma unroll
        for (int j = 0; j < 4; j++)
            bf[j] = ldf(Bs + (wn + j * 16 + l15) * 32 + quad * 8);
#pragma unroll
        for (int i = 0; i < 4; i++)
#pragma unroll
            for (int j = 0; j < 4; j++)
                acc[i][j] = __builtin_amdgcn_mfma_f32_16x16x32_bf16(af[i], bf[j], acc[i][j], 0, 0, 0);
    }
#pragma unroll
    for (int i = 0; i < 4; i++)
#pragma unroll
        for (int j = 0; j < 4; j++) {
            int col = bn + wn + j * 16 + l15;
#pragma unroll
            for (int r = 0; r < 4; r++) {
                int row = bm + wm + i * 16 + quad * 4 + r;
                float v = acc[i][j][r] + Res[(size_t)row * N + col];
                C[(size_t)row * N + col] = scrub(v, sval);
            }
        }
}

// -------- Dual GEMM + gated GELU: C = gelu(A@B1t^T) * (A@B2t^T), bf16 ------
__global__ __launch_bounds__(256) void gemm_dual_gelu(const u16* __restrict__ A,
                                                      const u16* __restrict__ B1t,
                                                      const u16* __restrict__ B2t,
                                                      u16* __restrict__ C,
                                                      int M, int N, int K) {
    __shared__ __align__(16) u16 As[128 * 32];
    __shared__ __align__(16) u16 B1s[128 * 32];
    __shared__ __align__(16) u16 B2s[128 * 32];
    int tid = threadIdx.x;
    int wave = tid >> 6, lane = tid & 63, quad = lane >> 4, l15 = lane & 15;
    int bm = blockIdx.y * 128, bn = blockIdx.x * 128;
    int wm = (wave >> 1) * 64, wn = (wave & 1) * 64;
    f32x4 acc1[4][4] = {};
    f32x4 acc2[4][4] = {};
    int srow = wave * 32 + (lane >> 2), scol = (lane & 3) * 8;
    const u16* ga = A + (size_t)(bm + srow) * K + scol;
    const u16* g1 = B1t + (size_t)(bn + srow) * K + scol;
    const u16* g2 = B2t + (size_t)(bn + srow) * K + scol;
    u16* la = As + wave * 1024;
    u16* l1 = B1s + wave * 1024;
    u16* l2 = B2s + wave * 1024;
    for (int k0 = 0; k0 < K; k0 += 32) {
        __syncthreads();
        gld16(ga + k0, la);   gld16(ga + k0 + 16 * K, la + 512);
        gld16(g1 + k0, l1);   gld16(g1 + k0 + 16 * K, l1 + 512);
        gld16(g2 + k0, l2);   gld16(g2 + k0 + 16 * K, l2 + 512);
        __syncthreads();
        short8 af[4], b1f[4], b2f_[4];
#pragma unroll
        for (int i = 0; i < 4; i++)
            af[i] = ldf(As + (wm + i * 16 + l15) * 32 + quad * 8);
#pragma unroll
        for (int j = 0; j < 4; j++) {
            b1f[j] = ldf(B1s + (wn + j * 16 + l15) * 32 + quad * 8);
            b2f_[j] = ldf(B2s + (wn + j * 16 + l15) * 32 + quad * 8);
        }
#pragma unroll
        for (int i = 0; i < 4; i++)
#pragma unroll
            for (int j = 0; j < 4; j++) {
                acc1[i][j] = __builtin_amdgcn_mfma_f32_16x16x32_bf16(af[i], b1f[j], acc1[i][j], 0, 0, 0);
                acc2[i][j] = __builtin_amdgcn_mfma_f32_16x16x32_bf16(af[i], b2f_[j], acc2[i][j], 0, 0, 0);
            }
    }
#pragma unroll
    for (int i = 0; i < 4; i++)
#pragma unroll
        for (int j = 0; j < 4; j++) {
            int col = bn + wn + j * 16 + l15;
#pragma unroll
            for (int r = 0; r < 4; r++) {
                int row = bm + wm + i * 16 + quad * 4 + r;
                float v = gelu_new_f(acc1[i][j][r]) * acc2[i][j][r];
                C[(size_t)row * N + col] = f2b(scrub(v, 1e10f));
            }
        }
}

// -------- MFMA flash attention; Q fp32, K hi/lo planes, V transposed -------
// grid (S/64, H, B), 256 thr. Per wave: 16 q-rows, full D=64, online softmax.
__global__ __launch_bounds__(256) void attn_kernel(const float* __restrict__ Qb,
                                                   const u16* __restrict__ Kh,
                                                   const u16* __restrict__ Kl,
                                                   const u16* __restrict__ vT,
                                                   const float* __restrict__ bias_tab,
                                                   const float* __restrict__ mask_add,
                                                   u16* __restrict__ Ctx) {
    constexpr int QS = 72;
    __shared__ __align__(16) u16 Qhs[64 * QS];
    __shared__ __align__(16) u16 Qls[64 * QS];
    __shared__ __align__(16) u16 Khs[32 * 64];
    __shared__ __align__(16) u16 Kls[32 * 64];
    __shared__ __align__(16) u16 Vs[64 * 32];   // [d][kv]
    __shared__ __align__(16) u16 Pss[4 * 16 * 40];
    int tid = threadIdx.x, wave = tid >> 6, lane = tid & 63;
    int quad = lane >> 4, l15 = lane & 15;
    int h = blockIdx.y, b = blockIdx.z;
    int q0 = blockIdx.x * 64;
    const float* Qg = Qb + ((size_t)(b * 2048 + q0)) * 1024 + h * 64;
    {   // stage Q tile 64x64 fp32 -> hi/lo (once per block)
        int r = tid >> 2, c0 = (tid & 3) * 16;
#pragma unroll
        for (int j = 0; j < 4; j++) {
            float4 q4 = *(const float4*)(Qg + (size_t)r * 1024 + c0 + j * 4);
            u16 hh, ll;
            split_hl(q4.x, hh, ll); Qhs[r * QS + c0 + j * 4 + 0] = hh; Qls[r * QS + c0 + j * 4 + 0] = ll;
            split_hl(q4.y, hh, ll); Qhs[r * QS + c0 + j * 4 + 1] = hh; Qls[r * QS + c0 + j * 4 + 1] = ll;
            split_hl(q4.z, hh, ll); Qhs[r * QS + c0 + j * 4 + 2] = hh; Qls[r * QS + c0 + j * 4 + 2] = ll;
            split_hl(q4.w, hh, ll); Qhs[r * QS + c0 + j * 4 + 3] = hh; Qls[r * QS + c0 + j * 4 + 3] = ll;
        }
    }
    f32x4 O[4] = {};
    float m_i[4], l_i[4];
#pragma unroll
    for (int r = 0; r < 4; r++) { m_i[r] = -1e9f; l_i[r] = 0.0f; }
    __syncthreads();
    short8 qh0 = ldf(Qhs + (wave * 16 + l15) * QS + quad * 8);
    short8 qh1 = ldf(Qhs + (wave * 16 + l15) * QS + 32 + quad * 8);
    short8 ql0 = ldf(Qls + (wave * 16 + l15) * QS + quad * 8);
    short8 ql1 = ldf(Qls + (wave * 16 + l15) * QS + 32 + quad * 8);
    u16* Pw = Pss + wave * 16 * 40;
    int my_q = q0 + wave * 16 + quad * 4;
    const float* bt = bias_tab + h * 4096;
    const float* ma = mask_add + b * 2048;
    // staging pointers (per-lane global, wave-uniform LDS base)
    const u16* gkh = Kh + ((size_t)(b * 2048 + wave * 8 + (lane >> 3))) * 1024 + h * 64 + (lane & 7) * 8;
    const u16* gkl = Kl + ((size_t)(b * 2048 + wave * 8 + (lane >> 3))) * 1024 + h * 64 + (lane & 7) * 8;
    const u16* gv  = vT + ((size_t)(h * 64 + wave * 16 + (lane >> 2))) * 4096 + b * 2048 + (lane & 3) * 8;
    u16* lkh = Khs + wave * 512;
    u16* lkl = Kls + wave * 512;
    u16* lv  = Vs + wave * 512;

    for (int k0 = 0; k0 < 2048; k0 += 32) {
        __syncthreads();
        gld16(gkh + (size_t)k0 * 1024, lkh);
        gld16(gkl + (size_t)k0 * 1024, lkl);
        gld16(gv + k0, lv);
        __syncthreads();
        float sv[2][4];
#pragma unroll
        for (int t = 0; t < 2; t++) {
            short8 kh0 = ldf(Khs + (t * 16 + l15) * 64 + quad * 8);
            short8 kh1 = ldf(Khs + (t * 16 + l15) * 64 + 32 + quad * 8);
            short8 kl0 = ldf(Kls + (t * 16 + l15) * 64 + quad * 8);
            short8 kl1 = ldf(Kls + (t * 16 + l15) * 64 + 32 + quad * 8);
            f32x4 z = {0.0f, 0.0f, 0.0f, 0.0f};
            z = __builtin_amdgcn_mfma_f32_16x16x32_bf16(ql0, kh0, z, 0, 0, 0);
            z = __builtin_amdgcn_mfma_f32_16x16x32_bf16(ql1, kh1, z, 0, 0, 0);
            z = __builtin_amdgcn_mfma_f32_16x16x32_bf16(qh0, kl0, z, 0, 0, 0);
            z = __builtin_amdgcn_mfma_f32_16x16x32_bf16(qh1, kl1, z, 0, 0, 0);
            z = __builtin_amdgcn_mfma_f32_16x16x32_bf16(qh0, kh0, z, 0, 0, 0);
            z = __builtin_amdgcn_mfma_f32_16x16x32_bf16(qh1, kh1, z, 0, 0, 0);
            int kcol = k0 + t * 16 + l15;
            float madd = ma[kcol];
#pragma unroll
            for (int r = 0; r < 4; r++)
                sv[t][r] = z[r] + bt[kcol - (my_q + r) + 2047] + madd;
        }
#pragma unroll
        for (int r = 0; r < 4; r++) {
            float mx = fmaxf(sv[0][r], sv[1][r]);
#pragma unroll
            for (int off = 1; off < 16; off <<= 1) mx = fmaxf(mx, __shfl_xor(mx, off, 64));
            float mnew = fmaxf(m_i[r], mx);
            float a = __expf(m_i[r] - mnew);
            float p0 = __expf(sv[0][r] - mnew);
            float p1 = __expf(sv[1][r] - mnew);
            sv[0][r] = p0; sv[1][r] = p1;
            float rsum = p0 + p1;
#pragma unroll
            for (int off = 1; off < 16; off <<= 1) rsum += __shfl_xor(rsum, off, 64);
            l_i[r] = l_i[r] * a + rsum;
            m_i[r] = mnew;
#pragma unroll
            for (int nt = 0; nt < 4; nt++) O[nt][r] *= a;
        }
        // P: C-layout -> LDS -> A-layout (wave-local region)
#pragma unroll
        for (int t = 0; t < 2; t++)
#pragma unroll
            for (int r = 0; r < 4; r++)
                Pw[(quad * 4 + r) * 40 + t * 16 + l15] = f2b(sv[t][r]);
        short8 pf = ldf(Pw + l15 * 40 + quad * 8);
#pragma unroll
        for (int nt = 0; nt < 4; nt++) {
            short8 vf = ldf(Vs + (nt * 16 + l15) * 32 + quad * 8);
            O[nt] = __builtin_amdgcn_mfma_f32_16x16x32_bf16(pf, vf, O[nt], 0, 0, 0);
        }
    }
    u16* Cg = Ctx + ((size_t)(b * 2048 + my_q)) * 1024 + h * 64;
#pragma unroll
    for (int nt = 0; nt < 4; nt++)
#pragma unroll
        for (int r = 0; r < 4; r++) {
            float v = O[nt][r] / l_i[r];
            Cg[(size_t)r * 1024 + nt * 16 + l15] = f2b(scrub(v, 1e6f));
        }
}

// ---------------------------------------------------------------------------
extern "C" void kernel_launch(void* const* d_in, const int* in_sizes, int n_in,
                              void* d_out, int out_size, void* d_ws, size_t ws_size,
                              hipStream_t stream) {
    const float* hidden = (const float*)d_in[0];
    const float* mask   = (const float*)d_in[1];
    const float* ln1_w  = (const float*)d_in[2];
    const float* wq     = (const float*)d_in[3];
    const float* wk     = (const float*)d_in[4];
    const float* wv     = (const float*)d_in[5];
    const float* relb   = (const float*)d_in[6];
    const float* wo     = (const float*)d_in[7];
    const float* ln2_w  = (const float*)d_in[8];
    const float* w1     = (const float*)d_in[9];
    const float* w2     = (const float*)d_in[10];
    const float* w_out  = (const float*)d_in[11];
    float* out = (float*)d_out;

    // workspace layout (MB), phase-multiplexed (peak 64.3 MB):
    //  0- 6 : qkvT (P0-P2)            -> woutT (0-8, after out-proj)
    //  6- 8 : woT (P0-P4)
    //  8-16 : w1T (P0-P6)
    // 16-24 : w2T (P0-P6)
    // 24-32 : normedh (P1-P2) -> ctx (P3-P4) -> normed2 (P5-P6)
    // 32-40 : normedl (P1-P2) \
    // 40-48 : Kh (P2-P3)        \ ffg (32-64, P6-P7)
    // 48-56 : Kl (P2-P3)        /
    // 56-64 : vT (P2-P3)      /
    // 64-   : bias_tab (256K) + mask_add (16K)
    // Q (fp32) lives in d_out until out-proj overwrites it with the trunk.
    char* w = (char*)d_ws;
    const size_t MB = 1u << 20;
    u16*   qkvT    = (u16*)(w + 0 * MB);
    u16*   woutT   = (u16*)(w + 0 * MB);
    u16*   woT     = (u16*)(w + 6 * MB);
    u16*   w1T     = (u16*)(w + 8 * MB);
    u16*   w2T     = (u16*)(w + 16 * MB);
    u16*   normedh = (u16*)(w + 24 * MB);
    u16*   ctx     = (u16*)(w + 24 * MB);
    u16*   normed2 = (u16*)(w + 24 * MB);
    u16*   normedl = (u16*)(w + 32 * MB);
    u16*   Kh      = (u16*)(w + 40 * MB);
    u16*   Kl      = (u16*)(w + 48 * MB);
    u16*   vT      = (u16*)(w + 56 * MB);
    u16*   ffg     = (u16*)(w + 32 * MB);
    float* bias_tab = (float*)(w + 64 * MB);
    float* mask_add = (float*)(w + 64 * MB + 256 * 1024);
    float* qb      = (float*)d_out;

    dim3 blk(256);
    // weight transposes fp32 -> bf16 [N][K]; wq/wk/wv into one qkvT [3072][1024]
    transpose_cvt<<<dim3(32, 32), blk, 0, stream>>>(wq, qkvT, 1024, 1024);
    transpose_cvt<<<dim3(32, 32), blk, 0, stream>>>(wk, qkvT + 1024 * 1024, 1024, 1024);
    transpose_cvt<<<dim3(32, 32), blk, 0, stream>>>(wv, qkvT + 2048 * 1024, 1024, 1024);
    transpose_cvt<<<dim3(32, 32), blk, 0, stream>>>(wo, woT, 1024, 1024);
    transpose_cvt<<<dim3(128, 32), blk, 0, stream>>>(w1, w1T, 1024, 4096);
    transpose_cvt<<<dim3(128, 32), blk, 0, stream>>>(w2, w2T, 1024, 4096);
    bias_table_kernel<<<16, 256, 0, stream>>>(relb, mask, bias_tab, mask_add);

    // pre-LN 1 (hi+lo planes) + merged QKV projection
    rmsnorm_k<<<4096, blk, 0, stream>>>(hidden, ln1_w, normedh, normedl);
    gemm_qkv<<<dim3(24, 32), blk, 0, stream>>>(normedh, normedl, qkvT, qb, Kh, Kl, vT);

    // attention (ctx overwrites dead normedh region)
    attn_kernel<<<dim3(32, 16, 2), blk, 0, stream>>>(qb, Kh, Kl, vT, bias_tab, mask_add, ctx);

    // output proj + residual -> fp32 trunk in d_out (overwrites qb)
    gemm_bt_res<<<dim3(8, 32), blk, 0, stream>>>(ctx, woT, out, hidden, 4096, 1024, 1024, 1e8f);

    // transpose w_out into now-dead qkvT/woT region
    transpose_cvt<<<dim3(32, 128), blk, 0, stream>>>(w_out, woutT, 4096, 1024);

    // pre-LN 2 (single plane) + gated FFN + final residual
    rmsnorm_k<<<4096, blk, 0, stream>>>(out, ln2_w, normed2, nullptr);
    gemm_dual_gelu<<<dim3(32, 32), blk, 0, stream>>>(normed2, w1T, w2T, ffg, 4096, 4096, 1024);
    gemm_bt_res<<<dim3(8, 32), blk, 0, stream>>>(ffg, woutT, out, out, 4096, 1024, 4096, 1e12f);
}

// Round 5
// 677.327 us; speedup vs baseline: 1.3031x; 1.1334x over previous
//
#include <hip/hip_runtime.h>
#include <math.h>

typedef unsigned short u16;
typedef unsigned int u32;
typedef __attribute__((ext_vector_type(8))) short short8; // 8 x bf16 (4 VGPRs)
typedef __attribute__((ext_vector_type(4))) float f32x4;

__device__ __forceinline__ float b2f(u16 u) {
    u32 x = ((u32)u) << 16;
    return __builtin_bit_cast(float, x);
}
__device__ __forceinline__ u16 f2b(float f) { // RNE bf16
    u32 x = __builtin_bit_cast(u32, f);
    u32 r = x + 0x7fffu + ((x >> 16) & 1u);
    return (u16)(r >> 16);
}
__device__ __forceinline__ void split_hl(float x, u16& h, u16& l) {
    u16 hb = f2b(x);
    h = hb;
    l = f2b(x - b2f(hb));
}
__device__ __forceinline__ float gelu_new_f(float x) {
    const float c = 0.7978845608028654f;
    return 0.5f * x * (1.0f + tanhf(c * (x + 0.044715f * x * x * x)));
}
// breadcrumb: NaN OR inf -> stage-distinctive magnitude
__device__ __forceinline__ float scrub(float v, float s) {
    return (fabsf(v) < 1e25f) ? v : s;
}
// async global->LDS, 16B per lane; LDS dest = wave-uniform base + lane*16
__device__ __forceinline__ void gld16(const void* g, void* l) {
    __builtin_amdgcn_global_load_lds((const __attribute__((address_space(1))) u32*)g,
                                     (__attribute__((address_space(3))) u32*)l,
                                     16, 0, 0);
}
__device__ __forceinline__ short8 ldf(const u16* p) { return *(const short8*)p; }

// -------- transpose+convert: src fp32 [R][C] -> dst bf16 [C][R] ------------
__global__ __launch_bounds__(256) void transpose_cvt(const float* __restrict__ src,
                                                     u16* __restrict__ dst, int R, int C) {
    __shared__ u16 t[32][33];
    int c0 = blockIdx.x * 32, r0 = blockIdx.y * 32;
    int x = threadIdx.x & 31, y = threadIdx.x >> 5; // 32 x 8
#pragma unroll
    for (int i = 0; i < 32; i += 8)
        t[y + i][x] = f2b(src[(size_t)(r0 + y + i) * C + c0 + x]);
    __syncthreads();
#pragma unroll
    for (int i = 0; i < 32; i += 8)
        dst[(size_t)(c0 + y + i) * R + r0 + x] = t[x][y + i];
}

// -------- T5 rel-pos bias table + additive mask (fp32 inputs) --------------
// mask_add has the softmax fixed shift (-20) folded in.
__global__ void bias_table_kernel(const float* __restrict__ rel_bias,
                                  const float* __restrict__ mask,
                                  float* __restrict__ tab,
                                  float* __restrict__ mask_add) {
    int idx = blockIdx.x * 256 + threadIdx.x; // 0..4095
    if (idx < 4095) {
        int rel = idx - 2047;
        int ret = rel > 0 ? 16 : 0;
        int n = rel < 0 ? -rel : rel;
        int bucket;
        if (n < 8) {
            bucket = ret + n;
        } else {
            int v = 8 + (int)(logf((float)n * 0.125f) * (8.0f / 2.7725887222397811f));
            v = v < 15 ? v : 15;
            bucket = ret + v;
        }
#pragma unroll
        for (int h = 0; h < 16; h++)
            tab[h * 4096 + idx] = rel_bias[bucket * 16 + h];
    }
    if (idx < 4096)
        mask_add[idx] = (1.0f - mask[idx]) * -10000.0f - 20.0f;
}

// -------- RMSNorm: fp32 in -> bf16 hi (+ optional lo plane) ----------------
__global__ __launch_bounds__(256) void rmsnorm_k(const float* __restrict__ X,
                                                 const float* __restrict__ W,
                                                 u16* __restrict__ Yh,
                                                 u16* __restrict__ Yl) {
    __shared__ float red[4];
    int row = blockIdx.x, tid = threadIdx.x;
    const float* xr = X + (size_t)row * 1024;
    float4 x = *(const float4*)(xr + tid * 4);
    float ss = x.x * x.x + x.y * x.y + x.z * x.z + x.w * x.w;
#pragma unroll
    for (int off = 32; off; off >>= 1) ss += __shfl_xor(ss, off, 64);
    if ((tid & 63) == 0) red[tid >> 6] = ss;
    __syncthreads();
    float tot = red[0] + red[1] + red[2] + red[3];
    float s = rsqrtf(tot * (1.0f / 1024.0f) + 1e-6f);
    float4 w4 = *(const float4*)(W + tid * 4);
    float y0 = scrub(x.x * s * w4.x, 1e3f);
    float y1 = scrub(x.y * s * w4.y, 1e3f);
    float y2 = scrub(x.z * s * w4.z, 1e3f);
    float y3 = scrub(x.w * s * w4.w, 1e3f);
    u16 h0, h1, h2, h3, l0, l1, l2, l3;
    split_hl(y0, h0, l0); split_hl(y1, h1, l1);
    split_hl(y2, h2, l2); split_hl(y3, h3, l3);
    uint2 oh, ol;
    oh.x = (u32)h0 | ((u32)h1 << 16);
    oh.y = (u32)h2 | ((u32)h3 << 16);
    *(uint2*)(Yh + (size_t)row * 1024 + tid * 4) = oh;
    if (Yl) {
        ol.x = (u32)l0 | ((u32)l1 << 16);
        ol.y = (u32)l2 | ((u32)l3 << 16);
        *(uint2*)(Yl + (size_t)row * 1024 + tid * 4) = ol;
    }
}

// -------- merged QKV GEMM, split-A hi/lo, K=1024, N=3072 -------------------
// epilogue: Q -> fp32 qb; K -> bf16 hi/lo planes; V -> transposed bf16 vT
__global__ __launch_bounds__(256) void gemm_qkv(const u16* __restrict__ Ah,
                                                const u16* __restrict__ Al,
                                                const u16* __restrict__ Bt,
                                                float* __restrict__ qb,
                                                u16* __restrict__ Kh,
                                                u16* __restrict__ Kl,
                                                u16* __restrict__ vT) {
    const int K = 1024;
    __shared__ __align__(16) u16 Ash[128 * 32];
    __shared__ __align__(16) u16 Asl[128 * 32];
    __shared__ __align__(16) u16 Bs[128 * 32];
    int tid = threadIdx.x;
    int wave = tid >> 6, lane = tid & 63, quad = lane >> 4, l15 = lane & 15;
    int bm = blockIdx.y * 128, bn = blockIdx.x * 128;
    int wm = (wave >> 1) * 64, wn = (wave & 1) * 64;
    f32x4 acc[4][4] = {};
    int srow = wave * 32 + (lane >> 2), scol = (lane & 3) * 8;
    const u16* gah = Ah + (size_t)(bm + srow) * K + scol;
    const u16* gal = Al + (size_t)(bm + srow) * K + scol;
    const u16* gb  = Bt + (size_t)(bn + srow) * K + scol;
    u16* lah = Ash + wave * 1024;
    u16* lal = Asl + wave * 1024;
    u16* lb  = Bs  + wave * 1024;
    for (int k0 = 0; k0 < K; k0 += 32) {
        __syncthreads();
        gld16(gah + k0, lah);           gld16(gah + k0 + 16 * K, lah + 512);
        gld16(gal + k0, lal);           gld16(gal + k0 + 16 * K, lal + 512);
        gld16(gb + k0, lb);             gld16(gb + k0 + 16 * K, lb + 512);
        __syncthreads();
        short8 afh[4], afl[4], bf[4];
#pragma unroll
        for (int i = 0; i < 4; i++) {
            afh[i] = ldf(Ash + (wm + i * 16 + l15) * 32 + quad * 8);
            afl[i] = ldf(Asl + (wm + i * 16 + l15) * 32 + quad * 8);
        }
#pragma unroll
        for (int j = 0; j < 4; j++)
            bf[j] = ldf(Bs + (wn + j * 16 + l15) * 32 + quad * 8);
#pragma unroll
        for (int i = 0; i < 4; i++)
#pragma unroll
            for (int j = 0; j < 4; j++) {
                acc[i][j] = __builtin_amdgcn_mfma_f32_16x16x32_bf16(afh[i], bf[j], acc[i][j], 0, 0, 0);
                acc[i][j] = __builtin_amdgcn_mfma_f32_16x16x32_bf16(afl[i], bf[j], acc[i][j], 0, 0, 0);
            }
    }
    if (bn < 1024) {            // Q -> fp32
#pragma unroll
        for (int i = 0; i < 4; i++)
#pragma unroll
            for (int j = 0; j < 4; j++) {
                int col = bn + wn + j * 16 + l15;
#pragma unroll
                for (int r = 0; r < 4; r++) {
                    int row = bm + wm + i * 16 + quad * 4 + r;
                    qb[(size_t)row * 1024 + col] = scrub(acc[i][j][r], 1e4f);
                }
            }
    } else if (bn < 2048) {     // K -> hi/lo bf16 planes
#pragma unroll
        for (int i = 0; i < 4; i++)
#pragma unroll
            for (int j = 0; j < 4; j++) {
                int col = bn - 1024 + wn + j * 16 + l15;
#pragma unroll
                for (int r = 0; r < 4; r++) {
                    int row = bm + wm + i * 16 + quad * 4 + r;
                    u16 hh, ll;
                    split_hl(scrub(acc[i][j][r], 1e4f), hh, ll);
                    Kh[(size_t)row * 1024 + col] = hh;
                    Kl[(size_t)row * 1024 + col] = ll;
                }
            }
    } else {                    // V -> transposed bf16 vT[d][B*S]
#pragma unroll
        for (int i = 0; i < 4; i++)
#pragma unroll
            for (int j = 0; j < 4; j++) {
                int col = bn - 2048 + wn + j * 16 + l15;
                int row0 = bm + wm + i * 16 + quad * 4;
                ushort4 p;
                p.x = f2b(scrub(acc[i][j][0], 1e4f));
                p.y = f2b(scrub(acc[i][j][1], 1e4f));
                p.z = f2b(scrub(acc[i][j][2], 1e4f));
                p.w = f2b(scrub(acc[i][j][3], 1e4f));
                *(ushort4*)(vT + (size_t)col * 4096 + row0) = p;
            }
    }
}

// -------- GEMM: C fp32 = A bf16 [M,K] @ Bt [N,K]^T + Res fp32 --------------
__global__ __launch_bounds__(256) void gemm_bt_res(const u16* __restrict__ A,
                                                   const u16* __restrict__ Bt,
                                                   float* __restrict__ C,
                                                   const float* __restrict__ Res,
                                                   int M, int N, int K, float sval) {
    __shared__ __align__(16) u16 As[128 * 32];
    __shared__ __align__(16) u16 Bs[128 * 32];
    int tid = threadIdx.x;
    int wave = tid >> 6, lane = tid & 63, quad = lane >> 4, l15 = lane & 15;
    int bm = blockIdx.y * 128, bn = blockIdx.x * 128;
    int wm = (wave >> 1) * 64, wn = (wave & 1) * 64;
    f32x4 acc[4][4] = {};
    int srow = wave * 32 + (lane >> 2), scol = (lane & 3) * 8;
    const u16* ga = A + (size_t)(bm + srow) * K + scol;
    const u16* gb = Bt + (size_t)(bn + srow) * K + scol;
    u16* la = As + wave * 1024;
    u16* lb = Bs + wave * 1024;
    for (int k0 = 0; k0 < K; k0 += 32) {
        __syncthreads();
        gld16(ga + k0, la);   gld16(ga + k0 + 16 * K, la + 512);
        gld16(gb + k0, lb);   gld16(gb + k0 + 16 * K, lb + 512);
        __syncthreads();
        short8 af[4], bf[4];
#pragma unroll
        for (int i = 0; i < 4; i++)
            af[i] = ldf(As + (wm + i * 16 + l15) * 32 + quad * 8);
#pragma unroll
        for (int j = 0; j < 4; j++)
            bf[j] = ldf(Bs + (wn + j * 16 + l15) * 32 + quad * 8);
#pragma unroll
        for (int i = 0; i < 4; i++)
#pragma unroll
            for (int j = 0; j < 4; j++)
                acc[i][j] = __builtin_amdgcn_mfma_f32_16x16x32_bf16(af[i], bf[j], acc[i][j], 0, 0, 0);
    }
#pragma unroll
    for (int i = 0; i < 4; i++)
#pragma unroll
        for (int j = 0; j < 4; j++) {
            int col = bn + wn + j * 16 + l15;
#pragma unroll
            for (int r = 0; r < 4; r++) {
                int row = bm + wm + i * 16 + quad * 4 + r;
                float v = acc[i][j][r] + Res[(size_t)row * N + col];
                C[(size_t)row * N + col] = scrub(v, sval);
            }
        }
}

// -------- Dual GEMM + gated GELU: C = gelu(A@B1t^T) * (A@B2t^T), bf16 ------
__global__ __launch_bounds__(256) void gemm_dual_gelu(const u16* __restrict__ A,
                                                      const u16* __restrict__ B1t,
                                                      const u16* __restrict__ B2t,
                                                      u16* __restrict__ C,
                                                      int M, int N, int K) {
    __shared__ __align__(16) u16 As[128 * 32];
    __shared__ __align__(16) u16 B1s[128 * 32];
    __shared__ __align__(16) u16 B2s[128 * 32];
    int tid = threadIdx.x;
    int wave = tid >> 6, lane = tid & 63, quad = lane >> 4, l15 = lane & 15;
    int bm = blockIdx.y * 128, bn = blockIdx.x * 128;
    int wm = (wave >> 1) * 64, wn = (wave & 1) * 64;
    f32x4 acc1[4][4] = {};
    f32x4 acc2[4][4] = {};
    int srow = wave * 32 + (lane >> 2), scol = (lane & 3) * 8;
    const u16* ga = A + (size_t)(bm + srow) * K + scol;
    const u16* g1 = B1t + (size_t)(bn + srow) * K + scol;
    const u16* g2 = B2t + (size_t)(bn + srow) * K + scol;
    u16* la = As + wave * 1024;
    u16* l1 = B1s + wave * 1024;
    u16* l2 = B2s + wave * 1024;
    for (int k0 = 0; k0 < K; k0 += 32) {
        __syncthreads();
        gld16(ga + k0, la);   gld16(ga + k0 + 16 * K, la + 512);
        gld16(g1 + k0, l1);   gld16(g1 + k0 + 16 * K, l1 + 512);
        gld16(g2 + k0, l2);   gld16(g2 + k0 + 16 * K, l2 + 512);
        __syncthreads();
        short8 af[4], b1f[4], b2f_[4];
#pragma unroll
        for (int i = 0; i < 4; i++)
            af[i] = ldf(As + (wm + i * 16 + l15) * 32 + quad * 8);
#pragma unroll
        for (int j = 0; j < 4; j++) {
            b1f[j] = ldf(B1s + (wn + j * 16 + l15) * 32 + quad * 8);
            b2f_[j] = ldf(B2s + (wn + j * 16 + l15) * 32 + quad * 8);
        }
#pragma unroll
        for (int i = 0; i < 4; i++)
#pragma unroll
            for (int j = 0; j < 4; j++) {
                acc1[i][j] = __builtin_amdgcn_mfma_f32_16x16x32_bf16(af[i], b1f[j], acc1[i][j], 0, 0, 0);
                acc2[i][j] = __builtin_amdgcn_mfma_f32_16x16x32_bf16(af[i], b2f_[j], acc2[i][j], 0, 0, 0);
            }
    }
#pragma unroll
    for (int i = 0; i < 4; i++)
#pragma unroll
        for (int j = 0; j < 4; j++) {
            int col = bn + wn + j * 16 + l15;
#pragma unroll
            for (int r = 0; r < 4; r++) {
                int row = bm + wm + i * 16 + quad * 4 + r;
                float v = gelu_new_f(acc1[i][j][r]) * acc2[i][j][r];
                C[(size_t)row * N + col] = f2b(scrub(v, 1e10f));
            }
        }
}

// -------- MFMA flash attention, fixed-shift softmax, swizzled staging ------
// grid (S/64, H, B), 256 thr. No online max: p = exp(s - 20) (shift folded
// into mask_add); row-sum l computed by MFMA with all-ones B fragment.
// K/V tiles staged via gld16 with XOR-swizzled 16B blocks -> conflict-free
// (K) / 4-way (V) ds_read_b128 fragment loads.
__global__ __launch_bounds__(256) void attn_kernel(const float* __restrict__ Qb,
                                                   const u16* __restrict__ Kh,
                                                   const u16* __restrict__ Kl,
                                                   const u16* __restrict__ vT,
                                                   const float* __restrict__ bias_tab,
                                                   const float* __restrict__ mask_add,
                                                   u16* __restrict__ Ctx) {
    constexpr int QS = 72;
    __shared__ __align__(16) u16 Qhs[64 * QS];
    __shared__ __align__(16) u16 Qls[64 * QS];
    __shared__ __align__(16) u16 Khs[32 * 64];  // swizzled: blk ^= (row&7)
    __shared__ __align__(16) u16 Kls[32 * 64];  // swizzled
    __shared__ __align__(16) u16 Vs[64 * 32];   // [d][kv], swizzled: blk ^= (row&3)
    __shared__ __align__(16) u16 Pss[4 * 16 * 40];
    int tid = threadIdx.x, wave = tid >> 6, lane = tid & 63;
    int quad = lane >> 4, l15 = lane & 15;
    int h = blockIdx.y, b = blockIdx.z;
    int q0 = blockIdx.x * 64;
    const float* Qg = Qb + ((size_t)(b * 2048 + q0)) * 1024 + h * 64;
    {   // stage Q tile 64x64 fp32 -> hi/lo (once per block)
        int r = tid >> 2, c0 = (tid & 3) * 16;
#pragma unroll
        for (int j = 0; j < 4; j++) {
            float4 q4 = *(const float4*)(Qg + (size_t)r * 1024 + c0 + j * 4);
            u16 hh, ll;
            split_hl(q4.x, hh, ll); Qhs[r * QS + c0 + j * 4 + 0] = hh; Qls[r * QS + c0 + j * 4 + 0] = ll;
            split_hl(q4.y, hh, ll); Qhs[r * QS + c0 + j * 4 + 1] = hh; Qls[r * QS + c0 + j * 4 + 1] = ll;
            split_hl(q4.z, hh, ll); Qhs[r * QS + c0 + j * 4 + 2] = hh; Qls[r * QS + c0 + j * 4 + 2] = ll;
            split_hl(q4.w, hh, ll); Qhs[r * QS + c0 + j * 4 + 3] = hh; Qls[r * QS + c0 + j * 4 + 3] = ll;
        }
    }
    f32x4 O[4] = {};
    f32x4 O4 = {};   // row-sums of P via ones-MFMA -> softmax denominator
    __syncthreads();
    short8 qh0 = ldf(Qhs + (wave * 16 + l15) * QS + quad * 8);
    short8 qh1 = ldf(Qhs + (wave * 16 + l15) * QS + 32 + quad * 8);
    short8 ql0 = ldf(Qls + (wave * 16 + l15) * QS + quad * 8);
    short8 ql1 = ldf(Qls + (wave * 16 + l15) * QS + 32 + quad * 8);
    short8 vones;
#pragma unroll
    for (int i = 0; i < 8; i++) vones[i] = (short)0x3f80; // bf16 1.0
    u16* Pw = Pss + wave * 16 * 40;
    int my_q = q0 + wave * 16 + quad * 4;
    const float* bt = bias_tab + h * 4096;
    const float* ma = mask_add + b * 2048;
    // swizzled staging source addresses (lane L fills LDS block L of its wave)
    const u16* gkh = Kh + ((size_t)(b * 2048 + wave * 8 + (lane >> 3))) * 1024 + h * 64
                       + (((lane & 7) ^ (lane >> 3)) * 8);
    const u16* gkl = Kl + ((size_t)(b * 2048 + wave * 8 + (lane >> 3))) * 1024 + h * 64
                       + (((lane & 7) ^ (lane >> 3)) * 8);
    const u16* gv  = vT + ((size_t)(h * 64 + wave * 16 + (lane >> 2))) * 4096 + b * 2048
                       + (((lane & 3) ^ ((lane >> 2) & 3)) * 8);
    u16* lkh = Khs + wave * 512;
    u16* lkl = Kls + wave * 512;
    u16* lv  = Vs + wave * 512;
    int swK0 = (quad ^ (l15 & 7)) * 8;        // kh0/kl0 block offset
    int swK1 = ((quad + 4) ^ (l15 & 7)) * 8;  // kh1/kl1 block offset
    int swV  = (quad ^ (l15 & 3)) * 8;

    for (int k0 = 0; k0 < 2048; k0 += 32) {
        __syncthreads();
        gld16(gkh + (size_t)k0 * 1024, lkh);
        gld16(gkl + (size_t)k0 * 1024, lkl);
        gld16(gv + k0, lv);
        __syncthreads();
        float pv[2][4];
#pragma unroll
        for (int t = 0; t < 2; t++) {
            const u16* krow = Khs + (t * 16 + l15) * 64;
            const u16* lrow = Kls + (t * 16 + l15) * 64;
            short8 kh0 = ldf(krow + swK0);
            short8 kh1 = ldf(krow + swK1);
            short8 kl0 = ldf(lrow + swK0);
            short8 kl1 = ldf(lrow + swK1);
            f32x4 z = {0.0f, 0.0f, 0.0f, 0.0f};
            z = __builtin_amdgcn_mfma_f32_16x16x32_bf16(ql0, kh0, z, 0, 0, 0);
            z = __builtin_amdgcn_mfma_f32_16x16x32_bf16(ql1, kh1, z, 0, 0, 0);
            z = __builtin_amdgcn_mfma_f32_16x16x32_bf16(qh0, kl0, z, 0, 0, 0);
            z = __builtin_amdgcn_mfma_f32_16x16x32_bf16(qh1, kl1, z, 0, 0, 0);
            z = __builtin_amdgcn_mfma_f32_16x16x32_bf16(qh0, kh0, z, 0, 0, 0);
            z = __builtin_amdgcn_mfma_f32_16x16x32_bf16(qh1, kh1, z, 0, 0, 0);
            int kcol = k0 + t * 16 + l15;
            float madd = ma[kcol];
#pragma unroll
            for (int r = 0; r < 4; r++)
                pv[t][r] = __expf(z[r] + bt[kcol - (my_q + r) + 2047] + madd);
        }
        // P: C-layout -> LDS -> A-layout (wave-local region)
#pragma unroll
        for (int t = 0; t < 2; t++)
#pragma unroll
            for (int r = 0; r < 4; r++)
                Pw[(quad * 4 + r) * 40 + t * 16 + l15] = f2b(pv[t][r]);
        short8 pf = ldf(Pw + l15 * 40 + quad * 8);
#pragma unroll
        for (int nt = 0; nt < 4; nt++) {
            short8 vf = ldf(Vs + (nt * 16 + l15) * 32 + swV);
            O[nt] = __builtin_amdgcn_mfma_f32_16x16x32_bf16(pf, vf, O[nt], 0, 0, 0);
        }
        O4 = __builtin_amdgcn_mfma_f32_16x16x32_bf16(pf, vones, O4, 0, 0, 0);
    }
    u16* Cg = Ctx + ((size_t)(b * 2048 + my_q)) * 1024 + h * 64;
#pragma unroll
    for (int nt = 0; nt < 4; nt++)
#pragma unroll
        for (int r = 0; r < 4; r++) {
            float v = O[nt][r] / fmaxf(O4[r], 1e-30f);
            Cg[(size_t)r * 1024 + nt * 16 + l15] = f2b(scrub(v, 1e6f));
        }
}

// ---------------------------------------------------------------------------
extern "C" void kernel_launch(void* const* d_in, const int* in_sizes, int n_in,
                              void* d_out, int out_size, void* d_ws, size_t ws_size,
                              hipStream_t stream) {
    const float* hidden = (const float*)d_in[0];
    const float* mask   = (const float*)d_in[1];
    const float* ln1_w  = (const float*)d_in[2];
    const float* wq     = (const float*)d_in[3];
    const float* wk     = (const float*)d_in[4];
    const float* wv     = (const float*)d_in[5];
    const float* relb   = (const float*)d_in[6];
    const float* wo     = (const float*)d_in[7];
    const float* ln2_w  = (const float*)d_in[8];
    const float* w1     = (const float*)d_in[9];
    const float* w2     = (const float*)d_in[10];
    const float* w_out  = (const float*)d_in[11];
    float* out = (float*)d_out;

    // workspace layout (MB), phase-multiplexed (peak ~64.3 MB):
    //  0- 6 : qkvT            -> woutT (0-8, after out-proj)
    //  6- 8 : woT
    //  8-16 : w1T   16-24 : w2T
    // 24-32 : normedh -> ctx -> normed2
    // 32-40 : normedl  \
    // 40-48 : Kh         \ ffg (32-64, FFN phase)
    // 48-56 : Kl         /
    // 56-64 : vT       /
    // 64-   : bias_tab (256K) + mask_add (16K)
    // Q (fp32) lives in d_out until out-proj overwrites it with the trunk.
    char* w = (char*)d_ws;
    const size_t MB = 1u << 20;
    u16*   qkvT    = (u16*)(w + 0 * MB);
    u16*   woutT   = (u16*)(w + 0 * MB);
    u16*   woT     = (u16*)(w + 6 * MB);
    u16*   w1T     = (u16*)(w + 8 * MB);
    u16*   w2T     = (u16*)(w + 16 * MB);
    u16*   normedh = (u16*)(w + 24 * MB);
    u16*   ctx     = (u16*)(w + 24 * MB);
    u16*   normed2 = (u16*)(w + 24 * MB);
    u16*   normedl = (u16*)(w + 32 * MB);
    u16*   Kh      = (u16*)(w + 40 * MB);
    u16*   Kl      = (u16*)(w + 48 * MB);
    u16*   vT      = (u16*)(w + 56 * MB);
    u16*   ffg     = (u16*)(w + 32 * MB);
    float* bias_tab = (float*)(w + 64 * MB);
    float* mask_add = (float*)(w + 64 * MB + 256 * 1024);
    float* qb      = (float*)d_out;

    dim3 blk(256);
    // weight transposes fp32 -> bf16 [N][K]; wq/wk/wv into one qkvT [3072][1024]
    transpose_cvt<<<dim3(32, 32), blk, 0, stream>>>(wq, qkvT, 1024, 1024);
    transpose_cvt<<<dim3(32, 32), blk, 0, stream>>>(wk, qkvT + 1024 * 1024, 1024, 1024);
    transpose_cvt<<<dim3(32, 32), blk, 0, stream>>>(wv, qkvT + 2048 * 1024, 1024, 1024);
    transpose_cvt<<<dim3(32, 32), blk, 0, stream>>>(wo, woT, 1024, 1024);
    transpose_cvt<<<dim3(128, 32), blk, 0, stream>>>(w1, w1T, 1024, 4096);
    transpose_cvt<<<dim3(128, 32), blk, 0, stream>>>(w2, w2T, 1024, 4096);
    bias_table_kernel<<<16, 256, 0, stream>>>(relb, mask, bias_tab, mask_add);

    // pre-LN 1 (hi+lo planes) + merged QKV projection
    rmsnorm_k<<<4096, blk, 0, stream>>>(hidden, ln1_w, normedh, normedl);
    gemm_qkv<<<dim3(24, 32), blk, 0, stream>>>(normedh, normedl, qkvT, qb, Kh, Kl, vT);

    // attention (ctx overwrites dead normedh region)
    attn_kernel<<<dim3(32, 16, 2), blk, 0, stream>>>(qb, Kh, Kl, vT, bias_tab, mask_add, ctx);

    // output proj + residual -> fp32 trunk in d_out (overwrites qb)
    gemm_bt_res<<<dim3(8, 32), blk, 0, stream>>>(ctx, woT, out, hidden, 4096, 1024, 1024, 1e8f);

    // transpose w_out into now-dead qkvT/woT region
    transpose_cvt<<<dim3(32, 128), blk, 0, stream>>>(w_out, woutT, 4096, 1024);

    // pre-LN 2 (single plane) + gated FFN + final residual
    rmsnorm_k<<<4096, blk, 0, stream>>>(out, ln2_w, normed2, nullptr);
    gemm_dual_gelu<<<dim3(32, 32), blk, 0, stream>>>(normed2, w1T, w2T, ffg, 4096, 4096, 1024);
    gemm_bt_res<<<dim3(8, 32), blk, 0, stream>>>(ffg, woutT, out, out, 4096, 1024, 4096, 1e12f);
}

// Round 6
// 557.602 us; speedup vs baseline: 1.5829x; 1.2147x over previous
//
#include <hip/hip_runtime.h>
#include <math.h>

typedef unsigned short u16;
typedef unsigned int u32;
typedef __attribute__((ext_vector_type(8))) short short8; // 8 x bf16 (4 VGPRs)
typedef __attribute__((ext_vector_type(4))) float f32x4;

__device__ __forceinline__ float b2f(u16 u) {
    u32 x = ((u32)u) << 16;
    return __builtin_bit_cast(float, x);
}
__device__ __forceinline__ u16 f2b(float f) { // RNE bf16
    u32 x = __builtin_bit_cast(u32, f);
    u32 r = x + 0x7fffu + ((x >> 16) & 1u);
    return (u16)(r >> 16);
}
__device__ __forceinline__ void split_hl(float x, u16& h, u16& l) {
    u16 hb = f2b(x);
    h = hb;
    l = f2b(x - b2f(hb));
}
// fast gelu_new: tanh(y) = 1 - 2/(1+e^{2y}) via __expf (inf-safe)
__device__ __forceinline__ float gelu_new_f(float x) {
    const float c = 0.7978845608028654f;
    float y = c * (x + 0.044715f * x * x * x);
    float t = 1.0f - 2.0f / (1.0f + __expf(2.0f * y));
    return 0.5f * x * (1.0f + t);
}
// breadcrumb: NaN OR inf -> stage-distinctive magnitude
__device__ __forceinline__ float scrub(float v, float s) {
    return (fabsf(v) < 1e25f) ? v : s;
}
// async global->LDS, 16B per lane; LDS dest = wave-uniform base + lane*16
__device__ __forceinline__ void gld16(const void* g, void* l) {
    __builtin_amdgcn_global_load_lds((const __attribute__((address_space(1))) u32*)g,
                                     (__attribute__((address_space(3))) u32*)l,
                                     16, 0, 0);
}
__device__ __forceinline__ short8 ldf(const u16* p) { return *(const short8*)p; }

// -------- transpose+convert: src fp32 [R][C] -> dst bf16 [C][R] ------------
__global__ __launch_bounds__(256) void transpose_cvt(const float* __restrict__ src,
                                                     u16* __restrict__ dst, int R, int C) {
    __shared__ u16 t[32][33];
    int c0 = blockIdx.x * 32, r0 = blockIdx.y * 32;
    int x = threadIdx.x & 31, y = threadIdx.x >> 5; // 32 x 8
#pragma unroll
    for (int i = 0; i < 32; i += 8)
        t[y + i][x] = f2b(src[(size_t)(r0 + y + i) * C + c0 + x]);
    __syncthreads();
#pragma unroll
    for (int i = 0; i < 32; i += 8)
        dst[(size_t)(c0 + y + i) * R + r0 + x] = t[x][y + i];
}

// -------- T5 rel-pos bias table + additive mask (fp32 inputs) --------------
// mask_add has the softmax fixed shift (-20) folded in.
__global__ void bias_table_kernel(const float* __restrict__ rel_bias,
                                  const float* __restrict__ mask,
                                  float* __restrict__ tab,
                                  float* __restrict__ mask_add) {
    int idx = blockIdx.x * 256 + threadIdx.x; // 0..4095
    if (idx < 4095) {
        int rel = idx - 2047;
        int ret = rel > 0 ? 16 : 0;
        int n = rel < 0 ? -rel : rel;
        int bucket;
        if (n < 8) {
            bucket = ret + n;
        } else {
            int v = 8 + (int)(logf((float)n * 0.125f) * (8.0f / 2.7725887222397811f));
            v = v < 15 ? v : 15;
            bucket = ret + v;
        }
#pragma unroll
        for (int h = 0; h < 16; h++)
            tab[h * 4096 + idx] = rel_bias[bucket * 16 + h];
    }
    if (idx < 4096)
        mask_add[idx] = (1.0f - mask[idx]) * -10000.0f - 20.0f;
}

// -------- RMSNorm: fp32 in -> bf16 ----------------------------------------
__global__ __launch_bounds__(256) void rmsnorm_k(const float* __restrict__ X,
                                                 const float* __restrict__ W,
                                                 u16* __restrict__ Y) {
    __shared__ float red[4];
    int row = blockIdx.x, tid = threadIdx.x;
    const float* xr = X + (size_t)row * 1024;
    float4 x = *(const float4*)(xr + tid * 4);
    float ss = x.x * x.x + x.y * x.y + x.z * x.z + x.w * x.w;
#pragma unroll
    for (int off = 32; off; off >>= 1) ss += __shfl_xor(ss, off, 64);
    if ((tid & 63) == 0) red[tid >> 6] = ss;
    __syncthreads();
    float tot = red[0] + red[1] + red[2] + red[3];
    float s = rsqrtf(tot * (1.0f / 1024.0f) + 1e-6f);
    float4 w4 = *(const float4*)(W + tid * 4);
    float y0 = scrub(x.x * s * w4.x, 1e3f);
    float y1 = scrub(x.y * s * w4.y, 1e3f);
    float y2 = scrub(x.z * s * w4.z, 1e3f);
    float y3 = scrub(x.w * s * w4.w, 1e3f);
    uint2 o;
    o.x = (u32)f2b(y0) | ((u32)f2b(y1) << 16);
    o.y = (u32)f2b(y2) | ((u32)f2b(y3) << 16);
    *(uint2*)(Y + (size_t)row * 1024 + tid * 4) = o;
}

// ===== BK=64 XOR-swizzled staging helpers ==================================
// LDS tile: 128 rows x 64 cols bf16 (16 KB), row stride 64 u16 (128 B).
// 16B block b of row r holds global col-block b^(r&7) -> conflict-free
// ds_read_b128 fragment loads. Staging: 4 gld16 per thread per buffer.
// source: row = bm|bn + wave*32 + g*8 + (lane>>3), colblk = (lane&7)^((lane>>3)&7)

// -------- merged QKV GEMM (single-plane A), K=1024, N=3072 -----------------
// epilogue: Q -> fp32 qb; K -> bf16 hi/lo planes; V -> transposed bf16 vT
__global__ __launch_bounds__(256) void gemm_qkv(const u16* __restrict__ A,
                                                const u16* __restrict__ Bt,
                                                float* __restrict__ qb,
                                                u16* __restrict__ Kh,
                                                u16* __restrict__ Kl,
                                                u16* __restrict__ vT) {
    const int K = 1024;
    __shared__ __align__(16) u16 As[128 * 64];
    __shared__ __align__(16) u16 Bs[128 * 64];
    int tid = threadIdx.x;
    int wave = tid >> 6, lane = tid & 63, quad = lane >> 4, l15 = lane & 15;
    int bm = blockIdx.y * 128, bn = blockIdx.x * 128;
    int wm = (wave >> 1) * 64, wn = (wave & 1) * 64;
    f32x4 acc[4][4] = {};
    int lr = lane >> 3, cb = (lane & 7) ^ (lr & 7);
    const u16* ga = A + (size_t)(bm + wave * 32 + lr) * K + cb * 8;
    const u16* gb = Bt + (size_t)(bn + wave * 32 + lr) * K + cb * 8;
    u16* la = As + wave * 2048;
    u16* lb = Bs + wave * 2048;
    int swz = l15 & 7;
    for (int k0 = 0; k0 < K; k0 += 64) {
        __syncthreads();
#pragma unroll
        for (int g = 0; g < 4; g++) {
            gld16(ga + k0 + (size_t)(g * 8) * K, la + g * 512);
            gld16(gb + k0 + (size_t)(g * 8) * K, lb + g * 512);
        }
        __syncthreads();
#pragma unroll
        for (int s = 0; s < 2; s++) {
            int kb = ((s * 4 + quad) ^ swz) * 8;
            short8 af[4], bf[4];
#pragma unroll
            for (int i = 0; i < 4; i++)
                af[i] = ldf(As + (wm + i * 16 + l15) * 64 + kb);
#pragma unroll
            for (int j = 0; j < 4; j++)
                bf[j] = ldf(Bs + (wn + j * 16 + l15) * 64 + kb);
#pragma unroll
            for (int i = 0; i < 4; i++)
#pragma unroll
                for (int j = 0; j < 4; j++)
                    acc[i][j] = __builtin_amdgcn_mfma_f32_16x16x32_bf16(af[i], bf[j], acc[i][j], 0, 0, 0);
        }
    }
    if (bn < 1024) {            // Q -> fp32
#pragma unroll
        for (int i = 0; i < 4; i++)
#pragma unroll
            for (int j = 0; j < 4; j++) {
                int col = bn + wn + j * 16 + l15;
#pragma unroll
                for (int r = 0; r < 4; r++) {
                    int row = bm + wm + i * 16 + quad * 4 + r;
                    qb[(size_t)row * 1024 + col] = scrub(acc[i][j][r], 1e4f);
                }
            }
    } else if (bn < 2048) {     // K -> hi/lo bf16 planes
#pragma unroll
        for (int i = 0; i < 4; i++)
#pragma unroll
            for (int j = 0; j < 4; j++) {
                int col = bn - 1024 + wn + j * 16 + l15;
#pragma unroll
                for (int r = 0; r < 4; r++) {
                    int row = bm + wm + i * 16 + quad * 4 + r;
                    u16 hh, ll;
                    split_hl(scrub(acc[i][j][r], 1e4f), hh, ll);
                    Kh[(size_t)row * 1024 + col] = hh;
                    Kl[(size_t)row * 1024 + col] = ll;
                }
            }
    } else {                    // V -> transposed bf16 vT[d][B*S]
#pragma unroll
        for (int i = 0; i < 4; i++)
#pragma unroll
            for (int j = 0; j < 4; j++) {
                int col = bn - 2048 + wn + j * 16 + l15;
                int row0 = bm + wm + i * 16 + quad * 4;
                ushort4 p;
                p.x = f2b(scrub(acc[i][j][0], 1e4f));
                p.y = f2b(scrub(acc[i][j][1], 1e4f));
                p.z = f2b(scrub(acc[i][j][2], 1e4f));
                p.w = f2b(scrub(acc[i][j][3], 1e4f));
                *(ushort4*)(vT + (size_t)col * 4096 + row0) = p;
            }
    }
}

// -------- GEMM: C fp32 = A bf16 [M,K] @ Bt [N,K]^T + Res fp32, BK=64 -------
__global__ __launch_bounds__(256) void gemm_bt_res(const u16* __restrict__ A,
                                                   const u16* __restrict__ Bt,
                                                   float* __restrict__ C,
                                                   const float* __restrict__ Res,
                                                   int M, int N, int K, float sval) {
    __shared__ __align__(16) u16 As[128 * 64];
    __shared__ __align__(16) u16 Bs[128 * 64];
    int tid = threadIdx.x;
    int wave = tid >> 6, lane = tid & 63, quad = lane >> 4, l15 = lane & 15;
    int bm = blockIdx.y * 128, bn = blockIdx.x * 128;
    int wm = (wave >> 1) * 64, wn = (wave & 1) * 64;
    f32x4 acc[4][4] = {};
    int lr = lane >> 3, cb = (lane & 7) ^ (lr & 7);
    const u16* ga = A + (size_t)(bm + wave * 32 + lr) * K + cb * 8;
    const u16* gb = Bt + (size_t)(bn + wave * 32 + lr) * K + cb * 8;
    u16* la = As + wave * 2048;
    u16* lb = Bs + wave * 2048;
    int swz = l15 & 7;
    for (int k0 = 0; k0 < K; k0 += 64) {
        __syncthreads();
#pragma unroll
        for (int g = 0; g < 4; g++) {
            gld16(ga + k0 + (size_t)(g * 8) * K, la + g * 512);
            gld16(gb + k0 + (size_t)(g * 8) * K, lb + g * 512);
        }
        __syncthreads();
#pragma unroll
        for (int s = 0; s < 2; s++) {
            int kb = ((s * 4 + quad) ^ swz) * 8;
            short8 af[4], bf[4];
#pragma unroll
            for (int i = 0; i < 4; i++)
                af[i] = ldf(As + (wm + i * 16 + l15) * 64 + kb);
#pragma unroll
            for (int j = 0; j < 4; j++)
                bf[j] = ldf(Bs + (wn + j * 16 + l15) * 64 + kb);
#pragma unroll
            for (int i = 0; i < 4; i++)
#pragma unroll
                for (int j = 0; j < 4; j++)
                    acc[i][j] = __builtin_amdgcn_mfma_f32_16x16x32_bf16(af[i], bf[j], acc[i][j], 0, 0, 0);
        }
    }
#pragma unroll
    for (int i = 0; i < 4; i++)
#pragma unroll
        for (int j = 0; j < 4; j++) {
            int col = bn + wn + j * 16 + l15;
#pragma unroll
            for (int r = 0; r < 4; r++) {
                int row = bm + wm + i * 16 + quad * 4 + r;
                float v = acc[i][j][r] + Res[(size_t)row * N + col];
                C[(size_t)row * N + col] = scrub(v, sval);
            }
        }
}

// -------- Dual GEMM + gated GELU: C = gelu(A@B1t^T) * (A@B2t^T), BK=64 -----
__global__ __launch_bounds__(256) void gemm_dual_gelu(const u16* __restrict__ A,
                                                      const u16* __restrict__ B1t,
                                                      const u16* __restrict__ B2t,
                                                      u16* __restrict__ C,
                                                      int M, int N, int K) {
    __shared__ __align__(16) u16 As[128 * 64];
    __shared__ __align__(16) u16 B1s[128 * 64];
    __shared__ __align__(16) u16 B2s[128 * 64];
    int tid = threadIdx.x;
    int wave = tid >> 6, lane = tid & 63, quad = lane >> 4, l15 = lane & 15;
    int bm = blockIdx.y * 128, bn = blockIdx.x * 128;
    int wm = (wave >> 1) * 64, wn = (wave & 1) * 64;
    f32x4 acc1[4][4] = {};
    f32x4 acc2[4][4] = {};
    int lr = lane >> 3, cb = (lane & 7) ^ (lr & 7);
    const u16* ga = A + (size_t)(bm + wave * 32 + lr) * K + cb * 8;
    const u16* g1 = B1t + (size_t)(bn + wave * 32 + lr) * K + cb * 8;
    const u16* g2 = B2t + (size_t)(bn + wave * 32 + lr) * K + cb * 8;
    u16* la = As + wave * 2048;
    u16* l1 = B1s + wave * 2048;
    u16* l2 = B2s + wave * 2048;
    int swz = l15 & 7;
    for (int k0 = 0; k0 < K; k0 += 64) {
        __syncthreads();
#pragma unroll
        for (int g = 0; g < 4; g++) {
            gld16(ga + k0 + (size_t)(g * 8) * K, la + g * 512);
            gld16(g1 + k0 + (size_t)(g * 8) * K, l1 + g * 512);
            gld16(g2 + k0 + (size_t)(g * 8) * K, l2 + g * 512);
        }
        __syncthreads();
#pragma unroll
        for (int s = 0; s < 2; s++) {
            int kb = ((s * 4 + quad) ^ swz) * 8;
            short8 af[4], b1f[4], b2f_[4];
#pragma unroll
            for (int i = 0; i < 4; i++)
                af[i] = ldf(As + (wm + i * 16 + l15) * 64 + kb);
#pragma unroll
            for (int j = 0; j < 4; j++) {
                b1f[j] = ldf(B1s + (wn + j * 16 + l15) * 64 + kb);
                b2f_[j] = ldf(B2s + (wn + j * 16 + l15) * 64 + kb);
            }
#pragma unroll
            for (int i = 0; i < 4; i++)
#pragma unroll
                for (int j = 0; j < 4; j++) {
                    acc1[i][j] = __builtin_amdgcn_mfma_f32_16x16x32_bf16(af[i], b1f[j], acc1[i][j], 0, 0, 0);
                    acc2[i][j] = __builtin_amdgcn_mfma_f32_16x16x32_bf16(af[i], b2f_[j], acc2[i][j], 0, 0, 0);
                }
        }
    }
#pragma unroll
    for (int i = 0; i < 4; i++)
#pragma unroll
        for (int j = 0; j < 4; j++) {
            int col = bn + wn + j * 16 + l15;
#pragma unroll
            for (int r = 0; r < 4; r++) {
                int row = bm + wm + i * 16 + quad * 4 + r;
                float v = gelu_new_f(acc1[i][j][r]) * acc2[i][j][r];
                C[(size_t)row * N + col] = f2b(scrub(v, 1e10f));
            }
        }
}

// -------- MFMA flash attention, fixed-shift softmax, swizzled staging ------
__global__ __launch_bounds__(256) void attn_kernel(const float* __restrict__ Qb,
                                                   const u16* __restrict__ Kh,
                                                   const u16* __restrict__ Kl,
                                                   const u16* __restrict__ vT,
                                                   const float* __restrict__ bias_tab,
                                                   const float* __restrict__ mask_add,
                                                   u16* __restrict__ Ctx) {
    constexpr int QS = 72;
    __shared__ __align__(16) u16 Qhs[64 * QS];
    __shared__ __align__(16) u16 Qls[64 * QS];
    __shared__ __align__(16) u16 Khs[32 * 64];  // swizzled: blk ^= (row&7)
    __shared__ __align__(16) u16 Kls[32 * 64];  // swizzled
    __shared__ __align__(16) u16 Vs[64 * 32];   // [d][kv], swizzled: blk ^= (row&3)
    __shared__ __align__(16) u16 Pss[4 * 16 * 40];
    int tid = threadIdx.x, wave = tid >> 6, lane = tid & 63;
    int quad = lane >> 4, l15 = lane & 15;
    int h = blockIdx.y, b = blockIdx.z;
    int q0 = blockIdx.x * 64;
    const float* Qg = Qb + ((size_t)(b * 2048 + q0)) * 1024 + h * 64;
    {   // stage Q tile 64x64 fp32 -> hi/lo (once per block)
        int r = tid >> 2, c0 = (tid & 3) * 16;
#pragma unroll
        for (int j = 0; j < 4; j++) {
            float4 q4 = *(const float4*)(Qg + (size_t)r * 1024 + c0 + j * 4);
            u16 hh, ll;
            split_hl(q4.x, hh, ll); Qhs[r * QS + c0 + j * 4 + 0] = hh; Qls[r * QS + c0 + j * 4 + 0] = ll;
            split_hl(q4.y, hh, ll); Qhs[r * QS + c0 + j * 4 + 1] = hh; Qls[r * QS + c0 + j * 4 + 1] = ll;
            split_hl(q4.z, hh, ll); Qhs[r * QS + c0 + j * 4 + 2] = hh; Qls[r * QS + c0 + j * 4 + 2] = ll;
            split_hl(q4.w, hh, ll); Qhs[r * QS + c0 + j * 4 + 3] = hh; Qls[r * QS + c0 + j * 4 + 3] = ll;
        }
    }
    f32x4 O[4] = {};
    f32x4 O4 = {};   // row-sums of P via ones-MFMA -> softmax denominator
    __syncthreads();
    short8 qh0 = ldf(Qhs + (wave * 16 + l15) * QS + quad * 8);
    short8 qh1 = ldf(Qhs + (wave * 16 + l15) * QS + 32 + quad * 8);
    short8 ql0 = ldf(Qls + (wave * 16 + l15) * QS + quad * 8);
    short8 ql1 = ldf(Qls + (wave * 16 + l15) * QS + 32 + quad * 8);
    short8 vones;
#pragma unroll
    for (int i = 0; i < 8; i++) vones[i] = (short)0x3f80; // bf16 1.0
    u16* Pw = Pss + wave * 16 * 40;
    int my_q = q0 + wave * 16 + quad * 4;
    const float* bt = bias_tab + h * 4096;
    const float* ma = mask_add + b * 2048;
    const u16* gkh = Kh + ((size_t)(b * 2048 + wave * 8 + (lane >> 3))) * 1024 + h * 64
                       + (((lane & 7) ^ (lane >> 3)) * 8);
    const u16* gkl = Kl + ((size_t)(b * 2048 + wave * 8 + (lane >> 3))) * 1024 + h * 64
                       + (((lane & 7) ^ (lane >> 3)) * 8);
    const u16* gv  = vT + ((size_t)(h * 64 + wave * 16 + (lane >> 2))) * 4096 + b * 2048
                       + (((lane & 3) ^ ((lane >> 2) & 3)) * 8);
    u16* lkh = Khs + wave * 512;
    u16* lkl = Kls + wave * 512;
    u16* lv  = Vs + wave * 512;
    int swK0 = (quad ^ (l15 & 7)) * 8;
    int swK1 = ((quad + 4) ^ (l15 & 7)) * 8;
    int swV  = (quad ^ (l15 & 3)) * 8;

    for (int k0 = 0; k0 < 2048; k0 += 32) {
        __syncthreads();
        gld16(gkh + (size_t)k0 * 1024, lkh);
        gld16(gkl + (size_t)k0 * 1024, lkl);
        gld16(gv + k0, lv);
        __syncthreads();
        float pv[2][4];
#pragma unroll
        for (int t = 0; t < 2; t++) {
            const u16* krow = Khs + (t * 16 + l15) * 64;
            const u16* lrow = Kls + (t * 16 + l15) * 64;
            short8 kh0 = ldf(krow + swK0);
            short8 kh1 = ldf(krow + swK1);
            short8 kl0 = ldf(lrow + swK0);
            short8 kl1 = ldf(lrow + swK1);
            f32x4 z = {0.0f, 0.0f, 0.0f, 0.0f};
            z = __builtin_amdgcn_mfma_f32_16x16x32_bf16(ql0, kh0, z, 0, 0, 0);
            z = __builtin_amdgcn_mfma_f32_16x16x32_bf16(ql1, kh1, z, 0, 0, 0);
            z = __builtin_amdgcn_mfma_f32_16x16x32_bf16(qh0, kl0, z, 0, 0, 0);
            z = __builtin_amdgcn_mfma_f32_16x16x32_bf16(qh1, kl1, z, 0, 0, 0);
            z = __builtin_amdgcn_mfma_f32_16x16x32_bf16(qh0, kh0, z, 0, 0, 0);
            z = __builtin_amdgcn_mfma_f32_16x16x32_bf16(qh1, kh1, z, 0, 0, 0);
            int kcol = k0 + t * 16 + l15;
            float madd = ma[kcol];
#pragma unroll
            for (int r = 0; r < 4; r++)
                pv[t][r] = __expf(z[r] + bt[kcol - (my_q + r) + 2047] + madd);
        }
#pragma unroll
        for (int t = 0; t < 2; t++)
#pragma unroll
            for (int r = 0; r < 4; r++)
                Pw[(quad * 4 + r) * 40 + t * 16 + l15] = f2b(pv[t][r]);
        short8 pf = ldf(Pw + l15 * 40 + quad * 8);
#pragma unroll
        for (int nt = 0; nt < 4; nt++) {
            short8 vf = ldf(Vs + (nt * 16 + l15) * 32 + swV);
            O[nt] = __builtin_amdgcn_mfma_f32_16x16x32_bf16(pf, vf, O[nt], 0, 0, 0);
        }
        O4 = __builtin_amdgcn_mfma_f32_16x16x32_bf16(pf, vones, O4, 0, 0, 0);
    }
    u16* Cg = Ctx + ((size_t)(b * 2048 + my_q)) * 1024 + h * 64;
#pragma unroll
    for (int nt = 0; nt < 4; nt++)
#pragma unroll
        for (int r = 0; r < 4; r++) {
            float v = O[nt][r] / fmaxf(O4[r], 1e-30f);
            Cg[(size_t)r * 1024 + nt * 16 + l15] = f2b(scrub(v, 1e6f));
        }
}

// ---------------------------------------------------------------------------
extern "C" void kernel_launch(void* const* d_in, const int* in_sizes, int n_in,
                              void* d_out, int out_size, void* d_ws, size_t ws_size,
                              hipStream_t stream) {
    const float* hidden = (const float*)d_in[0];
    const float* mask   = (const float*)d_in[1];
    const float* ln1_w  = (const float*)d_in[2];
    const float* wq     = (const float*)d_in[3];
    const float* wk     = (const float*)d_in[4];
    const float* wv     = (const float*)d_in[5];
    const float* relb   = (const float*)d_in[6];
    const float* wo     = (const float*)d_in[7];
    const float* ln2_w  = (const float*)d_in[8];
    const float* w1     = (const float*)d_in[9];
    const float* w2     = (const float*)d_in[10];
    const float* w_out  = (const float*)d_in[11];
    float* out = (float*)d_out;

    // workspace layout (MB), phase-multiplexed (peak ~64.3 MB):
    //  0- 6 : qkvT            -> woutT (0-8, after out-proj)
    //  6- 8 : woT
    //  8-16 : w1T   16-24 : w2T
    // 24-32 : normed -> ctx -> normed2
    // 32-40 : (free)   \
    // 40-48 : Kh         \ ffg (32-64, FFN phase)
    // 48-56 : Kl         /
    // 56-64 : vT       /
    // 64-   : bias_tab (256K) + mask_add (16K)
    // Q (fp32) lives in d_out until out-proj overwrites it with the trunk.
    char* w = (char*)d_ws;
    const size_t MB = 1u << 20;
    u16*   qkvT    = (u16*)(w + 0 * MB);
    u16*   woutT   = (u16*)(w + 0 * MB);
    u16*   woT     = (u16*)(w + 6 * MB);
    u16*   w1T     = (u16*)(w + 8 * MB);
    u16*   w2T     = (u16*)(w + 16 * MB);
    u16*   normed  = (u16*)(w + 24 * MB);
    u16*   ctx     = (u16*)(w + 24 * MB);
    u16*   normed2 = (u16*)(w + 24 * MB);
    u16*   Kh      = (u16*)(w + 40 * MB);
    u16*   Kl      = (u16*)(w + 48 * MB);
    u16*   vT      = (u16*)(w + 56 * MB);
    u16*   ffg     = (u16*)(w + 32 * MB);
    float* bias_tab = (float*)(w + 64 * MB);
    float* mask_add = (float*)(w + 64 * MB + 256 * 1024);
    float* qb      = (float*)d_out;

    dim3 blk(256);
    // weight transposes fp32 -> bf16 [N][K]; wq/wk/wv into one qkvT [3072][1024]
    transpose_cvt<<<dim3(32, 32), blk, 0, stream>>>(wq, qkvT, 1024, 1024);
    transpose_cvt<<<dim3(32, 32), blk, 0, stream>>>(wk, qkvT + 1024 * 1024, 1024, 1024);
    transpose_cvt<<<dim3(32, 32), blk, 0, stream>>>(wv, qkvT + 2048 * 1024, 1024, 1024);
    transpose_cvt<<<dim3(32, 32), blk, 0, stream>>>(wo, woT, 1024, 1024);
    transpose_cvt<<<dim3(128, 32), blk, 0, stream>>>(w1, w1T, 1024, 4096);
    transpose_cvt<<<dim3(128, 32), blk, 0, stream>>>(w2, w2T, 1024, 4096);
    bias_table_kernel<<<16, 256, 0, stream>>>(relb, mask, bias_tab, mask_add);

    // pre-LN 1 + merged QKV projection (single-plane A)
    rmsnorm_k<<<4096, blk, 0, stream>>>(hidden, ln1_w, normed);
    gemm_qkv<<<dim3(24, 32), blk, 0, stream>>>(normed, qkvT, qb, Kh, Kl, vT);

    // attention (ctx overwrites dead normed region)
    attn_kernel<<<dim3(32, 16, 2), blk, 0, stream>>>(qb, Kh, Kl, vT, bias_tab, mask_add, ctx);

    // output proj + residual -> fp32 trunk in d_out (overwrites qb)
    gemm_bt_res<<<dim3(8, 32), blk, 0, stream>>>(ctx, woT, out, hidden, 4096, 1024, 1024, 1e8f);

    // transpose w_out into now-dead qkvT/woT region
    transpose_cvt<<<dim3(32, 128), blk, 0, stream>>>(w_out, woutT, 4096, 1024);

    // pre-LN 2 + gated FFN + final residual
    rmsnorm_k<<<4096, blk, 0, stream>>>(out, ln2_w, normed2);
    gemm_dual_gelu<<<dim3(32, 32), blk, 0, stream>>>(normed2, w1T, w2T, ffg, 4096, 4096, 1024);
    gemm_bt_res<<<dim3(8, 32), blk, 0, stream>>>(ffg, woutT, out, out, 4096, 1024, 4096, 1e12f);
}